// Round 1
// baseline (955.172 us; speedup 1.0000x reference)
//
#include <hip/hip_runtime.h>
#include <hip/hip_bf16.h>
#include <math.h>

#define SEQ    2048
#define HIDDEN 2048
#define INTER  8192
#define NHEADS 16
#define KVH    8
#define HD     128

typedef __bf16 bf16x8 __attribute__((ext_vector_type(8)));
typedef __bf16 bf16x4 __attribute__((ext_vector_type(4)));
typedef float  f32x4  __attribute__((ext_vector_type(4)));

typedef __attribute__((address_space(1))) void* as1v;
typedef __attribute__((address_space(3))) void* as3v;

__device__ __forceinline__ void g2l16(const void* g, void* l) {
    __builtin_amdgcn_global_load_lds((as1v)g, (as3v)l, 16, 0, 0);
}

// weight blob layout (elements) inside ws: wq, wk, wv, wo, wg, wu, wd
#define OFF_WQ 0UL
#define OFF_WK 4194304UL
#define OFF_WV 6291456UL
#define OFF_WO 8388608UL
#define OFF_WG 12582912UL
#define OFF_WU 29360128UL
#define OFF_WD 46137344UL
#define W_TOTAL 62914560UL

// ---------------------------------------------------------------------------
// Weight fp32 -> bf16 conversion (once per launch).  8 elems/thread.
// ---------------------------------------------------------------------------
__global__ __launch_bounds__(256) void k_cvt(
        const float* __restrict__ wq, const float* __restrict__ wk,
        const float* __restrict__ wv, const float* __restrict__ wo,
        const float* __restrict__ wg, const float* __restrict__ wu,
        const float* __restrict__ wd, __bf16* __restrict__ wb) {
    size_t e = ((size_t)blockIdx.x * 256 + threadIdx.x) * 8;
    const float* src; size_t base;
    if      (e < OFF_WK) { src = wq; base = OFF_WQ; }
    else if (e < OFF_WV) { src = wk; base = OFF_WK; }
    else if (e < OFF_WO) { src = wv; base = OFF_WV; }
    else if (e < OFF_WG) { src = wo; base = OFF_WO; }
    else if (e < OFF_WU) { src = wg; base = OFF_WG; }
    else if (e < OFF_WD) { src = wu; base = OFF_WU; }
    else                 { src = wd; base = OFF_WD; }
    const float4* s = (const float4*)(src + (e - base));
    float4 a = s[0], b = s[1];
    bf16x8 o;
    o[0] = (__bf16)a.x; o[1] = (__bf16)a.y; o[2] = (__bf16)a.z; o[3] = (__bf16)a.w;
    o[4] = (__bf16)b.x; o[5] = (__bf16)b.y; o[6] = (__bf16)b.z; o[7] = (__bf16)b.w;
    *(bf16x8*)(wb + e) = o;
}

// ---------------------------------------------------------------------------
// RMSNorm (fp32 in) -> bf16 out.  One block per row of 2048.
// ---------------------------------------------------------------------------
__global__ __launch_bounds__(256) void k_rmsnorm(const float* __restrict__ x,
                                                 const float* __restrict__ w,
                                                 __bf16* __restrict__ out) {
    int row = blockIdx.x;
    int t   = threadIdx.x;
    const float4* xr = (const float4*)(x + (size_t)row * HIDDEN);
    float4 a = xr[t];
    float4 b = xr[t + 256];
    float ss = a.x*a.x + a.y*a.y + a.z*a.z + a.w*a.w
             + b.x*b.x + b.y*b.y + b.z*b.z + b.w*b.w;
#pragma unroll
    for (int d = 32; d > 0; d >>= 1) ss += __shfl_xor(ss, d);
    __shared__ float red[4];
    if ((t & 63) == 0) red[t >> 6] = ss;
    __syncthreads();
    float tot = red[0] + red[1] + red[2] + red[3];
    float r = rsqrtf(tot * (1.0f / (float)HIDDEN) + 1e-6f);
    const float4* wr = (const float4*)w;
    float4 wa = wr[t], wb = wr[t + 256];
    __bf16* o = out + (size_t)row * HIDDEN;
    bf16x4 pa, pb;
    pa[0] = (__bf16)(a.x * r * wa.x);
    pa[1] = (__bf16)(a.y * r * wa.y);
    pa[2] = (__bf16)(a.z * r * wa.z);
    pa[3] = (__bf16)(a.w * r * wa.w);
    pb[0] = (__bf16)(b.x * r * wb.x);
    pb[1] = (__bf16)(b.y * r * wb.y);
    pb[2] = (__bf16)(b.z * r * wb.z);
    pb[3] = (__bf16)(b.w * r * wb.w);
    *(bf16x4*)(o + 4*t)        = pa;
    *(bf16x4*)(o + 4*t + 1024) = pb;
}

// ---------------------------------------------------------------------------
// Pure-bf16 GEMM core, m97 structure: C[128x128] tile, A [M,K] bf16,
// B [N,K] bf16, both staged via global_load_lds width=16.  4 waves.
// Wave n-columns: wn*32 + (nt&1)*16 + (nt>>1)*64  (so RoPE partner col^64
// is acc[mt][nt^2], in-register, for the fused qkv epilogue).
// ---------------------------------------------------------------------------
__device__ __forceinline__ int gncol(int wn, int nt, int l15) {
    return wn*32 + ((nt & 1) << 4) + ((nt >> 1) << 6) + l15;
}

__device__ __forceinline__ void gemm_core(const __bf16* __restrict__ A, int lda,
                                          const __bf16* __restrict__ B, int ldb,
                                          int K, int m0, int n0,
                                          __bf16* As, __bf16* Bs,
                                          f32x4 acc[4][4]) {
    int tid  = threadIdx.x;
    int wave = tid >> 6;
    int lane = tid & 63;
    int quad = lane >> 4;
    int l15  = lane & 15;
    int wm = wave >> 1, wn = wave & 1;

    int srow = wave*32 + (lane >> 2);
    int scol = (lane & 3) * 8;
    char* adst = (char*)As + wave*2048 + lane*16;
    char* bdst = (char*)Bs + wave*2048 + lane*16;

    for (int k0 = 0; k0 < K; k0 += 32) {
        __syncthreads();
        g2l16(A + (size_t)(m0 + srow)      * lda + k0 + scol, adst);
        g2l16(A + (size_t)(m0 + srow + 16) * lda + k0 + scol, adst + 1024);
        g2l16(B + (size_t)(n0 + srow)      * ldb + k0 + scol, bdst);
        g2l16(B + (size_t)(n0 + srow + 16) * ldb + k0 + scol, bdst + 1024);
        __syncthreads();

        bf16x8 af[4], bfr[4];
#pragma unroll
        for (int mt = 0; mt < 4; ++mt)
            af[mt] = *(const bf16x8*)((const char*)As +
                        (wm*64 + mt*16 + l15)*64 + quad*16);
#pragma unroll
        for (int nt = 0; nt < 4; ++nt) {
            int r = gncol(wn, nt, l15);
            bfr[nt] = *(const bf16x8*)((const char*)Bs + r*64 + quad*16);
        }
#pragma unroll
        for (int mt = 0; mt < 4; ++mt)
#pragma unroll
            for (int nt = 0; nt < 4; ++nt)
                acc[mt][nt] = __builtin_amdgcn_mfma_f32_16x16x32_bf16(
                                  af[mt], bfr[nt], acc[mt][nt], 0, 0, 0);
    }
}

// Dual-B GEMM core: one K-loop, stages A once + two B matrices, accumulates
// into two 4x4 acc sets.  32 MFMA per staging round (vs 16), barriers/MFMA
// halved, A global traffic halved.
__device__ __forceinline__ void gemm_core_dual(
        const __bf16* __restrict__ A, int lda,
        const __bf16* __restrict__ B1, const __bf16* __restrict__ B2, int ldb,
        int K, int m0, int n0,
        __bf16* As, __bf16* B1s, __bf16* B2s,
        f32x4 acc1[4][4], f32x4 acc2[4][4]) {
    int tid  = threadIdx.x;
    int wave = tid >> 6;
    int lane = tid & 63;
    int quad = lane >> 4;
    int l15  = lane & 15;
    int wm = wave >> 1, wn = wave & 1;

    int srow = wave*32 + (lane >> 2);
    int scol = (lane & 3) * 8;
    char* adst  = (char*)As  + wave*2048 + lane*16;
    char* b1dst = (char*)B1s + wave*2048 + lane*16;
    char* b2dst = (char*)B2s + wave*2048 + lane*16;

    for (int k0 = 0; k0 < K; k0 += 32) {
        __syncthreads();
        g2l16(A  + (size_t)(m0 + srow)      * lda + k0 + scol, adst);
        g2l16(A  + (size_t)(m0 + srow + 16) * lda + k0 + scol, adst + 1024);
        g2l16(B1 + (size_t)(n0 + srow)      * ldb + k0 + scol, b1dst);
        g2l16(B1 + (size_t)(n0 + srow + 16) * ldb + k0 + scol, b1dst + 1024);
        g2l16(B2 + (size_t)(n0 + srow)      * ldb + k0 + scol, b2dst);
        g2l16(B2 + (size_t)(n0 + srow + 16) * ldb + k0 + scol, b2dst + 1024);
        __syncthreads();

        bf16x8 af[4], bfr[4];
#pragma unroll
        for (int mt = 0; mt < 4; ++mt)
            af[mt] = *(const bf16x8*)((const char*)As +
                        (wm*64 + mt*16 + l15)*64 + quad*16);
        // gate pass
#pragma unroll
        for (int nt = 0; nt < 4; ++nt) {
            int r = gncol(wn, nt, l15);
            bfr[nt] = *(const bf16x8*)((const char*)B1s + r*64 + quad*16);
        }
#pragma unroll
        for (int mt = 0; mt < 4; ++mt)
#pragma unroll
            for (int nt = 0; nt < 4; ++nt)
                acc1[mt][nt] = __builtin_amdgcn_mfma_f32_16x16x32_bf16(
                                   af[mt], bfr[nt], acc1[mt][nt], 0, 0, 0);
        // up pass (reuse bfr registers)
#pragma unroll
        for (int nt = 0; nt < 4; ++nt) {
            int r = gncol(wn, nt, l15);
            bfr[nt] = *(const bf16x8*)((const char*)B2s + r*64 + quad*16);
        }
#pragma unroll
        for (int mt = 0; mt < 4; ++mt)
#pragma unroll
            for (int nt = 0; nt < 4; ++nt)
                acc2[mt][nt] = __builtin_amdgcn_mfma_f32_16x16x32_bf16(
                                   af[mt], bfr[nt], acc2[mt][nt], 0, 0, 0);
    }
}

__device__ __forceinline__ void zero_acc(f32x4 acc[4][4]) {
#pragma unroll
    for (int i = 0; i < 4; ++i)
#pragma unroll
        for (int j = 0; j < 4; ++j) {
            acc[i][j][0] = 0.f; acc[i][j][1] = 0.f;
            acc[i][j][2] = 0.f; acc[i][j][3] = 0.f;
        }
}

// ---------------------------------------------------------------------------
// Fused QKV GEMM + RoPE + V-transpose.
// grid.x = 32 n-tiles: [0,16)=Q, [16,24)=K, [24,32)=V.
// Q written pre-scaled by HD^-0.5.  V written transposed [feat][pos] bf16.
// ---------------------------------------------------------------------------
__global__ __launch_bounds__(256) void k_gemm_qkv(
        const __bf16* __restrict__ x, const __bf16* __restrict__ wb,
        const int* __restrict__ pos_ids,
        __bf16* __restrict__ qb, __bf16* __restrict__ kb,
        __bf16* __restrict__ vtb) {
    __shared__ __bf16 As[128*32];
    __shared__ __bf16 Bs[128*32];
    int bn = blockIdx.x;
    int m0 = blockIdx.y * 128;
    const __bf16* B; int n0; int kind;
    if (bn < 16)      { B = wb + OFF_WQ; n0 = bn*128;      kind = 0; }
    else if (bn < 24) { B = wb + OFF_WK; n0 = (bn-16)*128; kind = 1; }
    else              { B = wb + OFF_WV; n0 = (bn-24)*128; kind = 2; }
    f32x4 acc[4][4]; zero_acc(acc);
    gemm_core(x, HIDDEN, B, HIDDEN, HIDDEN, m0, n0, As, Bs, acc);

    int tid = threadIdx.x, wave = tid >> 6, lane = tid & 63;
    int quad = lane >> 4, l15 = lane & 15, wm = wave >> 1, wn = wave & 1;

    if (kind == 2) {
        // V: transposed store, bf16x4 down the pos dimension
#pragma unroll
        for (int mt = 0; mt < 4; ++mt)
#pragma unroll
            for (int nt = 0; nt < 4; ++nt) {
                int f  = n0 + gncol(wn, nt, l15);
                int gm = m0 + wm*64 + mt*16 + quad*4;
                bf16x4 vv;
                vv[0] = (__bf16)acc[mt][nt][0];
                vv[1] = (__bf16)acc[mt][nt][1];
                vv[2] = (__bf16)acc[mt][nt][2];
                vv[3] = (__bf16)acc[mt][nt][3];
                *(bf16x4*)(vtb + (size_t)f*2048 + gm) = vv;
            }
    } else {
        __bf16* out = (kind == 0) ? qb : kb;
        int ldc     = (kind == 0) ? 2048 : 1024;
        float scale = (kind == 0) ? 0.08838834764831845f : 1.0f;
        // RoPE: d = wn*32 + (nt&1)*16 + (nt>>1)*64 + l15; i = d & 63
        int i0 = wn*32 + l15;
        const float LN1E4_64 = 0.14391156831212787f;
        float f0 = __expf(-LN1E4_64 * (float)i0);
        float f1 = __expf(-LN1E4_64 * (float)(i0 + 16));
#pragma unroll
        for (int mt = 0; mt < 4; ++mt)
#pragma unroll
            for (int r = 0; r < 4; ++r) {
                int gm = m0 + wm*64 + mt*16 + quad*4 + r;
                float pos = (float)pos_ids[gm];
                float s0, c0, s1, c1;
                __sincosf(pos * f0, &s0, &c0);
                __sincosf(pos * f1, &s1, &c1);
                float a0 = acc[mt][0][r], a1 = acc[mt][1][r];
                float a2 = acc[mt][2][r], a3 = acc[mt][3][r];
                size_t rowb = (size_t)gm * ldc + n0 + wn*32 + l15;
                out[rowb]      = (__bf16)((a0*c0 - a2*s0) * scale);
                out[rowb + 16] = (__bf16)((a1*c1 - a3*s1) * scale);
                out[rowb + 64] = (__bf16)((a2*c0 + a0*s0) * scale);
                out[rowb + 80] = (__bf16)((a3*c1 + a1*s1) * scale);
            }
    }
}

// ---------------------------------------------------------------------------
// O-projection + residual: h = resid + o @ wo^T  (fp32 out)
// ---------------------------------------------------------------------------
__global__ __launch_bounds__(256) void k_gemm_oproj(
        const __bf16* __restrict__ ob, const __bf16* __restrict__ wo,
        const float* __restrict__ resid, float* __restrict__ h) {
    __shared__ __bf16 As[128*32];
    __shared__ __bf16 Bs[128*32];
    int n0 = blockIdx.x * 128, m0 = blockIdx.y * 128;
    f32x4 acc[4][4]; zero_acc(acc);
    gemm_core(ob, HIDDEN, wo, HIDDEN, HIDDEN, m0, n0, As, Bs, acc);
    int lane = threadIdx.x & 63, wave = threadIdx.x >> 6;
    int quad = lane >> 4, l15 = lane & 15, wm = wave >> 1, wn = wave & 1;
#pragma unroll
    for (int mt = 0; mt < 4; ++mt)
#pragma unroll
        for (int nt = 0; nt < 4; ++nt)
#pragma unroll
            for (int r = 0; r < 4; ++r) {
                int gm = m0 + wm*64 + mt*16 + quad*4 + r;
                int gn = n0 + gncol(wn, nt, l15);
                size_t idx = (size_t)gm*HIDDEN + gn;
                h[idx] = acc[mt][nt][r] + resid[idx];
            }
}

// ---------------------------------------------------------------------------
// Gate+Up dual GEMM with fused SiLU: act = silu(y@wg^T) * (y@wu^T), bf16 out.
// Single K-loop: A staged once, both B tiles staged, 32 MFMA per barrier pair.
// ---------------------------------------------------------------------------
__global__ __launch_bounds__(256) void k_gemm_gateup(
        const __bf16* __restrict__ y, const __bf16* __restrict__ wg,
        const __bf16* __restrict__ wu, __bf16* __restrict__ act) {
    __shared__ __bf16 As[128*32];
    __shared__ __bf16 Bgs[128*32];
    __shared__ __bf16 Bus[128*32];
    int n0 = blockIdx.x * 128, m0 = blockIdx.y * 128;
    f32x4 ag[4][4]; zero_acc(ag);
    f32x4 au[4][4]; zero_acc(au);
    gemm_core_dual(y, HIDDEN, wg, wu, HIDDEN, HIDDEN, m0, n0,
                   As, Bgs, Bus, ag, au);
    int lane = threadIdx.x & 63, wave = threadIdx.x >> 6;
    int quad = lane >> 4, l15 = lane & 15, wm = wave >> 1, wn = wave & 1;
#pragma unroll
    for (int mt = 0; mt < 4; ++mt)
#pragma unroll
        for (int nt = 0; nt < 4; ++nt)
#pragma unroll
            for (int r = 0; r < 4; ++r) {
                int gm = m0 + wm*64 + mt*16 + quad*4 + r;
                int gn = n0 + gncol(wn, nt, l15);
                float g = ag[mt][nt][r];
                float u = au[mt][nt][r];
                float s = g / (1.0f + __expf(-g));
                act[(size_t)gm*INTER + gn] = (__bf16)(s * u);
            }
}

// ---------------------------------------------------------------------------
// Down GEMM + residual: out = h + act @ wd^T  (fp32 out), K = 8192
// ---------------------------------------------------------------------------
__global__ __launch_bounds__(256) void k_gemm_down(
        const __bf16* __restrict__ act, const __bf16* __restrict__ wd,
        const float* __restrict__ h, float* __restrict__ out) {
    __shared__ __bf16 As[128*32];
    __shared__ __bf16 Bs[128*32];
    int n0 = blockIdx.x * 128, m0 = blockIdx.y * 128;
    f32x4 acc[4][4]; zero_acc(acc);
    gemm_core(act, INTER, wd, INTER, INTER, m0, n0, As, Bs, acc);
    int lane = threadIdx.x & 63, wave = threadIdx.x >> 6;
    int quad = lane >> 4, l15 = lane & 15, wm = wave >> 1, wn = wave & 1;
#pragma unroll
    for (int mt = 0; mt < 4; ++mt)
#pragma unroll
        for (int nt = 0; nt < 4; ++nt)
#pragma unroll
            for (int r = 0; r < 4; ++r) {
                int gm = m0 + wm*64 + mt*16 + quad*4 + r;
                int gn = n0 + gncol(wn, nt, l15);
                size_t idx = (size_t)gm*HIDDEN + gn;
                out[idx] = acc[mt][nt][r] + h[idx];
            }
}

// ---------------------------------------------------------------------------
// Flash attention with same-sid + causal mask (window >= seq, always true).
// Block = (q-tile of 64, head).  4 waves, each owns 16 q rows.
// ---------------------------------------------------------------------------
__global__ __launch_bounds__(256) void k_attn(
        const __bf16* __restrict__ qb,   // [2048,2048] rope'd, pre-scaled
        const __bf16* __restrict__ kb,   // [2048,1024] rope'd
        const __bf16* __restrict__ vt,   // [1024][2048] transposed
        const int* __restrict__ sid,     // [2048]
        __bf16* __restrict__ o) {        // [2048,2048]
    __shared__ int    sid_lds[SEQ];        // 8KB
    __shared__ __bf16 Kt[64*128];          // 16KB [key][d]
    __shared__ __bf16 Vt[128*64];          // 16KB [d][key]
    __shared__ __bf16 Pl[4*1024];          // 8KB, per-wave 16x64

    int qt = blockIdx.x;          // 0..31
    int h  = blockIdx.y;          // 0..15
    int hk = h >> 1;              // GQA: rep=2
    int tid = threadIdx.x, wave = tid >> 6, lane = tid & 63;
    int quad = lane >> 4, l15 = lane & 15;
    int q0 = qt * 64;
    int qrow_base = q0 + wave * 16;

    for (int i = tid; i < SEQ; i += 256) sid_lds[i] = sid[i];

    bf16x8 qfrag[4];
#pragma unroll
    for (int seg = 0; seg < 4; ++seg)
        qfrag[seg] = *(const bf16x8*)(qb + (size_t)(qrow_base + l15)*2048
                                         + h*128 + seg*32 + quad*8);
    __syncthreads();
    int sq[4];
#pragma unroll
    for (int r = 0; r < 4; ++r) sq[r] = sid_lds[qrow_base + quad*4 + r];

    float m_i[4], l_i[4];
    f32x4 oacc[8];
#pragma unroll
    for (int r = 0; r < 4; ++r) { m_i[r] = -INFINITY; l_i[r] = 0.f; }
#pragma unroll
    for (int n = 0; n < 8; ++n) {
        oacc[n][0] = 0.f; oacc[n][1] = 0.f; oacc[n][2] = 0.f; oacc[n][3] = 0.f;
    }

    for (int kt = 0; kt <= qt; ++kt) {
        int k0 = kt * 64;
        __syncthreads();
#pragma unroll
        for (int t2 = 0; t2 < 4; ++t2) {
            int c   = wave*4 + t2;
            int row = c*4 + (lane >> 4);
            g2l16(kb + (size_t)(k0 + row)*1024 + hk*128 + (lane & 15)*8,
                  (char*)Kt + c*1024 + lane*16);
        }
#pragma unroll
        for (int t2 = 0; t2 < 4; ++t2) {
            int c   = wave*4 + t2;
            int row = c*8 + (lane >> 3);
            g2l16(vt + (size_t)(hk*128 + row)*2048 + k0 + (lane & 7)*8,
                  (char*)Vt + c*1024 + lane*16);
        }
        __syncthreads();

        f32x4 sacc[4];
#pragma unroll
        for (int nt = 0; nt < 4; ++nt) {
            sacc[nt][0]=0.f; sacc[nt][1]=0.f; sacc[nt][2]=0.f; sacc[nt][3]=0.f;
        }
#pragma unroll
        for (int seg = 0; seg < 4; ++seg)
#pragma unroll
            for (int nt = 0; nt < 4; ++nt) {
                bf16x8 kfr = *(const bf16x8*)((const char*)Kt +
                               (nt*16 + l15)*256 + seg*64 + quad*16);
                sacc[nt] = __builtin_amdgcn_mfma_f32_16x16x32_bf16(
                               qfrag[seg], kfr, sacc[nt], 0, 0, 0);
            }

        int sk[4], kg[4];
#pragma unroll
        for (int nt = 0; nt < 4; ++nt) {
            kg[nt] = k0 + nt*16 + l15;
            sk[nt] = sid_lds[kg[nt]];
        }
        float p[4][4];
#pragma unroll
        for (int r = 0; r < 4; ++r) {
            int qg = qrow_base + quad*4 + r;
            float mx = -INFINITY;
#pragma unroll
            for (int nt = 0; nt < 4; ++nt) {
                bool valid = (kg[nt] <= qg) && (sk[nt] == sq[r]);
                float s = valid ? sacc[nt][r] : -INFINITY;
                p[nt][r] = s;
                mx = fmaxf(mx, s);
            }
            mx = fmaxf(mx, __shfl_xor(mx, 1));
            mx = fmaxf(mx, __shfl_xor(mx, 2));
            mx = fmaxf(mx, __shfl_xor(mx, 4));
            mx = fmaxf(mx, __shfl_xor(mx, 8));
            float mn = fmaxf(m_i[r], mx);
            float alpha = (mn == m_i[r]) ? 1.0f : __expf(m_i[r] - mn);
            float rs = 0.f;
#pragma unroll
            for (int nt = 0; nt < 4; ++nt) {
                float pv = (p[nt][r] == -INFINITY) ? 0.f : __expf(p[nt][r] - mn);
                p[nt][r] = pv;
                rs += pv;
            }
            rs += __shfl_xor(rs, 1);
            rs += __shfl_xor(rs, 2);
            rs += __shfl_xor(rs, 4);
            rs += __shfl_xor(rs, 8);
            l_i[r] = l_i[r] * alpha + rs;
            m_i[r] = mn;
#pragma unroll
            for (int n = 0; n < 8; ++n) oacc[n][r] *= alpha;
        }

#pragma unroll
        for (int nt = 0; nt < 4; ++nt)
#pragma unroll
            for (int r = 0; r < 4; ++r)
                Pl[wave*1024 + (quad*4 + r)*64 + nt*16 + l15] = (__bf16)p[nt][r];
        __syncthreads();

#pragma unroll
        for (int kc = 0; kc < 2; ++kc) {
            bf16x8 pfrag = *(const bf16x8*)((const char*)Pl + wave*2048 +
                             l15*128 + kc*64 + quad*16);
#pragma unroll
            for (int n = 0; n < 8; ++n) {
                bf16x8 vfr = *(const bf16x8*)((const char*)Vt +
                               (n*16 + l15)*128 + kc*64 + quad*16);
                oacc[n] = __builtin_amdgcn_mfma_f32_16x16x32_bf16(
                              pfrag, vfr, oacc[n], 0, 0, 0);
            }
        }
    }

#pragma unroll
    for (int r = 0; r < 4; ++r) {
        float inv = 1.0f / l_i[r];
        size_t base = (size_t)(qrow_base + quad*4 + r)*2048 + h*128 + l15;
#pragma unroll
        for (int n = 0; n < 8; ++n)
            o[base + n*16] = (__bf16)(oacc[n][r] * inv);
    }
}

// ---------------------------------------------------------------------------
// Orchestration
// ---------------------------------------------------------------------------
extern "C" void kernel_launch(void* const* d_in, const int* in_sizes, int n_in,
                              void* d_out, int out_size, void* d_ws, size_t ws_size,
                              hipStream_t stream) {
    (void)in_sizes; (void)n_in; (void)out_size; (void)ws_size;
    const float* hidden = (const float*)d_in[0];
    const int*   sid    = (const int*)d_in[1];
    const int*   pos    = (const int*)d_in[2];
    const float* ln1    = (const float*)d_in[3];
    const float* wq     = (const float*)d_in[4];
    const float* wk     = (const float*)d_in[5];
    const float* wv     = (const float*)d_in[6];
    const float* wo     = (const float*)d_in[7];
    const float* ln2    = (const float*)d_in[8];
    const float* wg     = (const float*)d_in[9];
    const float* wu     = (const float*)d_in[10];
    const float* wd     = (const float*)d_in[11];
    float* out = (float*)d_out;
    char*  ws  = (char*)d_ws;

    // workspace layout, 176 MB total (lifetimes overlapped):
    __bf16* wb   = (__bf16*)(ws);                  // 0..120MB  weights bf16
    __bf16* xb   = (__bf16*)(ws + (120UL << 20));  // 120..128  x (rms1), later ob, later yb
    __bf16* qb   = (__bf16*)(ws + (128UL << 20));  // 128..136  q
    __bf16* kb   = (__bf16*)(ws + (136UL << 20));  // 136..140  k
    __bf16* vtb  = (__bf16*)(ws + (140UL << 20));  // 140..144  v^T
    __bf16* ob   = (__bf16*)(ws + (120UL << 20));  // reuse xb after qkv
    float*  hbuf = (float*) (ws + (128UL << 20));  // 128..144  reuse q/k/v after attn
    __bf16* yb   = (__bf16*)(ws + (120UL << 20));  // reuse ob after oproj
    __bf16* actb = (__bf16*)(ws + (144UL << 20));  // 144..176

    k_cvt<<<30720, 256, 0, stream>>>(wq, wk, wv, wo, wg, wu, wd, wb);
    k_rmsnorm<<<SEQ, 256, 0, stream>>>(hidden, ln1, xb);
    k_gemm_qkv<<<dim3(32, 16), 256, 0, stream>>>(xb, wb, pos, qb, kb, vtb);
    k_attn<<<dim3(32, 16), 256, 0, stream>>>(qb, kb, vtb, sid, ob);
    k_gemm_oproj<<<dim3(16, 16), 256, 0, stream>>>(ob, wb + OFF_WO, hidden, hbuf);
    k_rmsnorm<<<SEQ, 256, 0, stream>>>(hbuf, ln2, yb);
    k_gemm_gateup<<<dim3(64, 16), 256, 0, stream>>>(yb, wb + OFF_WG, wb + OFF_WU, actb);
    k_gemm_down<<<dim3(16, 16), 256, 0, stream>>>(actb, wb + OFF_WD, hbuf, out);
}

// Round 2
// 822.052 us; speedup vs baseline: 1.1619x; 1.1619x over previous
//
#include <hip/hip_runtime.h>
#include <hip/hip_bf16.h>
#include <math.h>

#define SEQ    2048
#define HIDDEN 2048
#define INTER  8192
#define NHEADS 16
#define KVH    8
#define HD     128

typedef __bf16 bf16x8 __attribute__((ext_vector_type(8)));
typedef __bf16 bf16x4 __attribute__((ext_vector_type(4)));
typedef float  f32x4  __attribute__((ext_vector_type(4)));

typedef __attribute__((address_space(1))) void* as1v;
typedef __attribute__((address_space(3))) void* as3v;

__device__ __forceinline__ void g2l16(const void* g, void* l) {
    __builtin_amdgcn_global_load_lds((as1v)g, (as3v)l, 16, 0, 0);
}

// weight blob layout (elements) inside ws: wq, wk, wv, wo, wg, wu, wd
#define OFF_WQ 0UL
#define OFF_WK 4194304UL
#define OFF_WV 6291456UL
#define OFF_WO 8388608UL
#define OFF_WG 12582912UL
#define OFF_WU 29360128UL
#define OFF_WD 46137344UL
#define W_TOTAL 62914560UL

// ---------------------------------------------------------------------------
// Weight fp32 -> bf16 conversion (once per launch).  8 elems/thread.
// ---------------------------------------------------------------------------
__global__ __launch_bounds__(256) void k_cvt(
        const float* __restrict__ wq, const float* __restrict__ wk,
        const float* __restrict__ wv, const float* __restrict__ wo,
        const float* __restrict__ wg, const float* __restrict__ wu,
        const float* __restrict__ wd, __bf16* __restrict__ wb) {
    size_t e = ((size_t)blockIdx.x * 256 + threadIdx.x) * 8;
    const float* src; size_t base;
    if      (e < OFF_WK) { src = wq; base = OFF_WQ; }
    else if (e < OFF_WV) { src = wk; base = OFF_WK; }
    else if (e < OFF_WO) { src = wv; base = OFF_WV; }
    else if (e < OFF_WG) { src = wo; base = OFF_WO; }
    else if (e < OFF_WU) { src = wg; base = OFF_WG; }
    else if (e < OFF_WD) { src = wu; base = OFF_WU; }
    else                 { src = wd; base = OFF_WD; }
    const float4* s = (const float4*)(src + (e - base));
    float4 a = s[0], b = s[1];
    bf16x8 o;
    o[0] = (__bf16)a.x; o[1] = (__bf16)a.y; o[2] = (__bf16)a.z; o[3] = (__bf16)a.w;
    o[4] = (__bf16)b.x; o[5] = (__bf16)b.y; o[6] = (__bf16)b.z; o[7] = (__bf16)b.w;
    *(bf16x8*)(wb + e) = o;
}

// ---------------------------------------------------------------------------
// RMSNorm (fp32 in) -> bf16 out.  One block per row of 2048.
// ---------------------------------------------------------------------------
__global__ __launch_bounds__(256) void k_rmsnorm(const float* __restrict__ x,
                                                 const float* __restrict__ w,
                                                 __bf16* __restrict__ out) {
    int row = blockIdx.x;
    int t   = threadIdx.x;
    const float4* xr = (const float4*)(x + (size_t)row * HIDDEN);
    float4 a = xr[t];
    float4 b = xr[t + 256];
    float ss = a.x*a.x + a.y*a.y + a.z*a.z + a.w*a.w
             + b.x*b.x + b.y*b.y + b.z*b.z + b.w*b.w;
#pragma unroll
    for (int d = 32; d > 0; d >>= 1) ss += __shfl_xor(ss, d);
    __shared__ float red[4];
    if ((t & 63) == 0) red[t >> 6] = ss;
    __syncthreads();
    float tot = red[0] + red[1] + red[2] + red[3];
    float r = rsqrtf(tot * (1.0f / (float)HIDDEN) + 1e-6f);
    const float4* wr = (const float4*)w;
    float4 wa = wr[t], wb = wr[t + 256];
    __bf16* o = out + (size_t)row * HIDDEN;
    bf16x4 pa, pb;
    pa[0] = (__bf16)(a.x * r * wa.x);
    pa[1] = (__bf16)(a.y * r * wa.y);
    pa[2] = (__bf16)(a.z * r * wa.z);
    pa[3] = (__bf16)(a.w * r * wa.w);
    pb[0] = (__bf16)(b.x * r * wb.x);
    pb[1] = (__bf16)(b.y * r * wb.y);
    pb[2] = (__bf16)(b.z * r * wb.z);
    pb[3] = (__bf16)(b.w * r * wb.w);
    *(bf16x4*)(o + 4*t)        = pa;
    *(bf16x4*)(o + 4*t + 1024) = pb;
}

// ---------------------------------------------------------------------------
// Pure-bf16 GEMM core, m97 structure (unchanged, proven): C[128x128] tile.
// ---------------------------------------------------------------------------
__device__ __forceinline__ int gncol(int wn, int nt, int l15) {
    return wn*32 + ((nt & 1) << 4) + ((nt >> 1) << 6) + l15;
}

__device__ __forceinline__ void gemm_core(const __bf16* __restrict__ A, int lda,
                                          const __bf16* __restrict__ B, int ldb,
                                          int K, int m0, int n0,
                                          __bf16* As, __bf16* Bs,
                                          f32x4 acc[4][4]) {
    int tid  = threadIdx.x;
    int wave = tid >> 6;
    int lane = tid & 63;
    int quad = lane >> 4;
    int l15  = lane & 15;
    int wm = wave >> 1, wn = wave & 1;

    int srow = wave*32 + (lane >> 2);
    int scol = (lane & 3) * 8;
    char* adst = (char*)As + wave*2048 + lane*16;
    char* bdst = (char*)Bs + wave*2048 + lane*16;

    for (int k0 = 0; k0 < K; k0 += 32) {
        __syncthreads();
        g2l16(A + (size_t)(m0 + srow)      * lda + k0 + scol, adst);
        g2l16(A + (size_t)(m0 + srow + 16) * lda + k0 + scol, adst + 1024);
        g2l16(B + (size_t)(n0 + srow)      * ldb + k0 + scol, bdst);
        g2l16(B + (size_t)(n0 + srow + 16) * ldb + k0 + scol, bdst + 1024);
        __syncthreads();

        bf16x8 af[4], bfr[4];
#pragma unroll
        for (int mt = 0; mt < 4; ++mt)
            af[mt] = *(const bf16x8*)((const char*)As +
                        (wm*64 + mt*16 + l15)*64 + quad*16);
#pragma unroll
        for (int nt = 0; nt < 4; ++nt) {
            int r = gncol(wn, nt, l15);
            bfr[nt] = *(const bf16x8*)((const char*)Bs + r*64 + quad*16);
        }
#pragma unroll
        for (int mt = 0; mt < 4; ++mt)
#pragma unroll
            for (int nt = 0; nt < 4; ++nt)
                acc[mt][nt] = __builtin_amdgcn_mfma_f32_16x16x32_bf16(
                                  af[mt], bfr[nt], acc[mt][nt], 0, 0, 0);
    }
}

__device__ __forceinline__ void zero_acc(f32x4 acc[4][4]) {
#pragma unroll
    for (int i = 0; i < 4; ++i)
#pragma unroll
        for (int j = 0; j < 4; ++j) {
            acc[i][j][0] = 0.f; acc[i][j][1] = 0.f;
            acc[i][j][2] = 0.f; acc[i][j][3] = 0.f;
        }
}

// ---------------------------------------------------------------------------
// 256x256-tile 8-phase pipelined GEMM (m201-style, plain HIP).
// 512 threads = 8 waves (2M x 4N); per-wave C = 128x64 laid out as
// (mh,nh) quadrant x (mt2 0..3, nt2 0..1) frags so EVERY wave reads both
// LDS halves of A and B each K-tile (required for the half-tile stage
// schedule to be race-free).  BK=64, double-buffered LDS = 128 KiB.
// LDS bank swizzle: chunk ^= (row&7), applied on the pre-swizzled global
// source (g2l16 dest must stay linear) and on the ds_read address.
// Counted vmcnt(4) at phases 4 and 8 only -- never drained to 0 in-loop.
// ---------------------------------------------------------------------------
#define MFMA_BF16 __builtin_amdgcn_mfma_f32_16x16x32_bf16
#define VMC asm volatile("s_waitcnt vmcnt(4)" ::: "memory")
#define NOSTMT ((void)0)

#define STAGE_A(BUF, HALF, TILE) do {                                         \
    const __bf16* _s = Aptr + (size_t)(m0 + (HALF)*128 + stgRow) * 2048       \
                      + ((size_t)(TILE) << 6) + stgCol;                       \
    char* _d = (char*)smem + (BUF)*65536 + (HALF)*16384 + stgDst;             \
    g2l16(_s, _d);                                                            \
    g2l16(_s + 8*2048, _d + 1024);                                            \
} while (0)

#define STAGE_B(BUF, HALF, TILE) do {                                         \
    const __bf16* _s = Bptr + (size_t)(n0 + (HALF)*128 + stgRow) * 2048       \
                      + ((size_t)(TILE) << 6) + stgCol;                       \
    char* _d = (char*)smem + (BUF)*65536 + 32768 + (HALF)*16384 + stgDst;     \
    g2l16(_s, _d);                                                            \
    g2l16(_s + 8*2048, _d + 1024);                                            \
} while (0)

#define PHASE(BUF, MH, NH, STAGE_STMT, VMWAIT) do {                           \
    bf16x8 _af[4][2], _bf[2][2];                                              \
    {                                                                         \
        const char* _Ab = (const char*)smem + (BUF)*65536 + (MH)*16384 + aRow;\
        const char* _Bb = (const char*)smem + (BUF)*65536 + 32768             \
                          + (NH)*16384 + bRow;                                \
        _Pragma("unroll")                                                     \
        for (int _m = 0; _m < 4; ++_m) {                                      \
            _af[_m][0] = *(const bf16x8*)(_Ab + _m*2048 + off0);              \
            _af[_m][1] = *(const bf16x8*)(_Ab + _m*2048 + (off0^64));         \
        }                                                                     \
        _Pragma("unroll")                                                     \
        for (int _n = 0; _n < 2; ++_n) {                                      \
            _bf[_n][0] = *(const bf16x8*)(_Bb + _n*2048 + off0);              \
            _bf[_n][1] = *(const bf16x8*)(_Bb + _n*2048 + (off0^64));         \
        }                                                                     \
    }                                                                         \
    STAGE_STMT;                                                               \
    VMWAIT;                                                                   \
    asm volatile("" ::: "memory");                                            \
    __builtin_amdgcn_s_barrier();                                             \
    asm volatile("" ::: "memory");                                            \
    __builtin_amdgcn_s_setprio(1);                                            \
    _Pragma("unroll")                                                         \
    for (int _m = 0; _m < 4; ++_m)                                            \
        _Pragma("unroll")                                                     \
        for (int _n = 0; _n < 2; ++_n) {                                      \
            acc[MH][NH][_m][_n] = MFMA_BF16(_af[_m][0], _bf[_n][0],           \
                                            acc[MH][NH][_m][_n], 0, 0, 0);    \
            acc[MH][NH][_m][_n] = MFMA_BF16(_af[_m][1], _bf[_n][1],           \
                                            acc[MH][NH][_m][_n], 0, 0, 0);    \
        }                                                                     \
    __builtin_amdgcn_s_setprio(0);                                            \
    asm volatile("" ::: "memory");                                            \
    __builtin_amdgcn_s_barrier();                                             \
    asm volatile("" ::: "memory");                                            \
} while (0)

// mode 0: outb = A@W^T (bf16).  mode 1: outb = silu(A@W^T) * outb (in place).
__global__ __launch_bounds__(512, 2) void k_mlp256(
        const __bf16* __restrict__ Aptr,   // [2048][2048] bf16
        const __bf16* __restrict__ Bptr,   // [8192][2048] bf16
        __bf16* __restrict__ outb,         // [2048][8192] bf16
        int mode) {
    __shared__ char smem[131072];

    // XCD-aware swizzle: 256 wgs, 8 XCDs, each XCD owns one 256-row m-stripe
    int flat = blockIdx.y * 32 + blockIdx.x;          // grid = (32, 8)
    int swz  = (flat & 7) * 32 + (flat >> 3);
    int m0 = (swz >> 5) * 256;
    int n0 = (swz & 31) * 256;

    int tid  = threadIdx.x;
    int wave = tid >> 6, lane = tid & 63;
    int wm = wave >> 2, wn = wave & 3;                // 2M x 4N waves
    int quad = lane >> 4, l15 = lane & 15;
    int cx   = l15 & 7;
    int off0 = (quad ^ cx) << 4;                      // swizzled 16B chunk, ks=0
    int aRow = (wm*64 + l15) << 7;                    // row*128B within half
    int bRow = (wn*32 + l15) << 7;
    int stgRow = wave*16 + (lane >> 3);               // staged row within half
    int stgCol = ((lane & 7) ^ (lane >> 3)) << 3;     // inverse-swizzled src col
    int stgDst = wave*2048 + lane*16;                 // linear LDS dest

    f32x4 acc[2][2][4][2];
#pragma unroll
    for (int a = 0; a < 2; ++a)
#pragma unroll
        for (int b = 0; b < 2; ++b)
#pragma unroll
            for (int c = 0; c < 4; ++c)
#pragma unroll
                for (int d = 0; d < 2; ++d) {
                    acc[a][b][c][d][0] = 0.f; acc[a][b][c][d][1] = 0.f;
                    acc[a][b][c][d][2] = 0.f; acc[a][b][c][d][3] = 0.f;
                }

    // prologue: tile0 all 4 halves -> buf0, tile1 A0/B0 -> buf1 (12 loads)
    STAGE_A(0, 0, 0); STAGE_B(0, 0, 0);
    STAGE_A(0, 1, 0); STAGE_B(0, 1, 0);
    STAGE_A(1, 0, 1); STAGE_B(1, 0, 1);
    VMC;                                              // tile0 landed; t1 in flight
    asm volatile("" ::: "memory");
    __builtin_amdgcn_s_barrier();
    asm volatile("" ::: "memory");

    const int NT = 32, TM = 31;                       // K = 2048, BK = 64
    for (int i = 0; i < NT/2; ++i) {
        int t1 = (2*i + 1) & TM;
        int t2 = (2*i + 2) & TM;
        int t3 = (2*i + 3) & TM;
        PHASE(0, 0, 0, STAGE_A(1, 1, t1), NOSTMT);    // P1
        PHASE(0, 0, 1, STAGE_B(1, 1, t1), NOSTMT);    // P2
        PHASE(0, 1, 0, STAGE_A(0, 0, t2), NOSTMT);    // P3
        PHASE(0, 1, 1, STAGE_B(0, 0, t2), VMC);       // P4
        PHASE(1, 0, 0, STAGE_A(0, 1, t2), NOSTMT);    // P5
        PHASE(1, 0, 1, STAGE_B(0, 1, t2), NOSTMT);    // P6
        PHASE(1, 1, 0, STAGE_A(1, 0, t3), NOSTMT);    // P7
        PHASE(1, 1, 1, STAGE_B(1, 0, t3), VMC);       // P8
    }

    // epilogue
    int gm0 = m0 + wm*64 + quad*4;
    int gn0 = n0 + wn*32 + l15;
    if (mode == 0) {
#pragma unroll
        for (int mh = 0; mh < 2; ++mh)
#pragma unroll
            for (int nh = 0; nh < 2; ++nh)
#pragma unroll
                for (int mt2 = 0; mt2 < 4; ++mt2)
#pragma unroll
                    for (int nt2 = 0; nt2 < 2; ++nt2)
#pragma unroll
                        for (int r = 0; r < 4; ++r) {
                            int gm = gm0 + mh*128 + mt2*16 + r;
                            int gn = gn0 + nh*128 + nt2*16;
                            outb[(size_t)gm*INTER + gn] =
                                (__bf16)acc[mh][nh][mt2][nt2][r];
                        }
    } else {
#pragma unroll
        for (int mh = 0; mh < 2; ++mh)
#pragma unroll
            for (int nh = 0; nh < 2; ++nh)
#pragma unroll
                for (int mt2 = 0; mt2 < 4; ++mt2)
#pragma unroll
                    for (int nt2 = 0; nt2 < 2; ++nt2)
#pragma unroll
                        for (int r = 0; r < 4; ++r) {
                            int gm = gm0 + mh*128 + mt2*16 + r;
                            int gn = gn0 + nh*128 + nt2*16;
                            size_t idx = (size_t)gm*INTER + gn;
                            float g = acc[mh][nh][mt2][nt2][r];
                            float u = (float)outb[idx];
                            float s = g / (1.0f + __expf(-g));
                            outb[idx] = (__bf16)(s * u);
                        }
    }
}

// ---------------------------------------------------------------------------
// Fused QKV GEMM + RoPE + V-transpose.
// ---------------------------------------------------------------------------
__global__ __launch_bounds__(256) void k_gemm_qkv(
        const __bf16* __restrict__ x, const __bf16* __restrict__ wb,
        const int* __restrict__ pos_ids,
        __bf16* __restrict__ qb, __bf16* __restrict__ kb,
        __bf16* __restrict__ vtb) {
    __shared__ __bf16 As[128*32];
    __shared__ __bf16 Bs[128*32];
    int bn = blockIdx.x;
    int m0 = blockIdx.y * 128;
    const __bf16* B; int n0; int kind;
    if (bn < 16)      { B = wb + OFF_WQ; n0 = bn*128;      kind = 0; }
    else if (bn < 24) { B = wb + OFF_WK; n0 = (bn-16)*128; kind = 1; }
    else              { B = wb + OFF_WV; n0 = (bn-24)*128; kind = 2; }
    f32x4 acc[4][4]; zero_acc(acc);
    gemm_core(x, HIDDEN, B, HIDDEN, HIDDEN, m0, n0, As, Bs, acc);

    int tid = threadIdx.x, wave = tid >> 6, lane = tid & 63;
    int quad = lane >> 4, l15 = lane & 15, wm = wave >> 1, wn = wave & 1;

    if (kind == 2) {
#pragma unroll
        for (int mt = 0; mt < 4; ++mt)
#pragma unroll
            for (int nt = 0; nt < 4; ++nt) {
                int f  = n0 + gncol(wn, nt, l15);
                int gm = m0 + wm*64 + mt*16 + quad*4;
                bf16x4 vv;
                vv[0] = (__bf16)acc[mt][nt][0];
                vv[1] = (__bf16)acc[mt][nt][1];
                vv[2] = (__bf16)acc[mt][nt][2];
                vv[3] = (__bf16)acc[mt][nt][3];
                *(bf16x4*)(vtb + (size_t)f*2048 + gm) = vv;
            }
    } else {
        __bf16* out = (kind == 0) ? qb : kb;
        int ldc     = (kind == 0) ? 2048 : 1024;
        float scale = (kind == 0) ? 0.08838834764831845f : 1.0f;
        int i0 = wn*32 + l15;
        const float LN1E4_64 = 0.14391156831212787f;
        float f0 = __expf(-LN1E4_64 * (float)i0);
        float f1 = __expf(-LN1E4_64 * (float)(i0 + 16));
#pragma unroll
        for (int mt = 0; mt < 4; ++mt)
#pragma unroll
            for (int r = 0; r < 4; ++r) {
                int gm = m0 + wm*64 + mt*16 + quad*4 + r;
                float pos = (float)pos_ids[gm];
                float s0, c0, s1, c1;
                __sincosf(pos * f0, &s0, &c0);
                __sincosf(pos * f1, &s1, &c1);
                float a0 = acc[mt][0][r], a1 = acc[mt][1][r];
                float a2 = acc[mt][2][r], a3 = acc[mt][3][r];
                size_t rowb = (size_t)gm * ldc + n0 + wn*32 + l15;
                out[rowb]      = (__bf16)((a0*c0 - a2*s0) * scale);
                out[rowb + 16] = (__bf16)((a1*c1 - a3*s1) * scale);
                out[rowb + 64] = (__bf16)((a2*c0 + a0*s0) * scale);
                out[rowb + 80] = (__bf16)((a3*c1 + a1*s1) * scale);
            }
    }
}

// ---------------------------------------------------------------------------
// O-projection + residual: h = resid + o @ wo^T  (fp32 out)
// ---------------------------------------------------------------------------
__global__ __launch_bounds__(256) void k_gemm_oproj(
        const __bf16* __restrict__ ob, const __bf16* __restrict__ wo,
        const float* __restrict__ resid, float* __restrict__ h) {
    __shared__ __bf16 As[128*32];
    __shared__ __bf16 Bs[128*32];
    int n0 = blockIdx.x * 128, m0 = blockIdx.y * 128;
    f32x4 acc[4][4]; zero_acc(acc);
    gemm_core(ob, HIDDEN, wo, HIDDEN, HIDDEN, m0, n0, As, Bs, acc);
    int lane = threadIdx.x & 63, wave = threadIdx.x >> 6;
    int quad = lane >> 4, l15 = lane & 15, wm = wave >> 1, wn = wave & 1;
#pragma unroll
    for (int mt = 0; mt < 4; ++mt)
#pragma unroll
        for (int nt = 0; nt < 4; ++nt)
#pragma unroll
            for (int r = 0; r < 4; ++r) {
                int gm = m0 + wm*64 + mt*16 + quad*4 + r;
                int gn = n0 + gncol(wn, nt, l15);
                size_t idx = (size_t)gm*HIDDEN + gn;
                h[idx] = acc[mt][nt][r] + resid[idx];
            }
}

// ---------------------------------------------------------------------------
// Down GEMM + residual: out = h + act @ wd^T  (fp32 out), K = 8192
// ---------------------------------------------------------------------------
__global__ __launch_bounds__(256) void k_gemm_down(
        const __bf16* __restrict__ act, const __bf16* __restrict__ wd,
        const float* __restrict__ h, float* __restrict__ out) {
    __shared__ __bf16 As[128*32];
    __shared__ __bf16 Bs[128*32];
    int n0 = blockIdx.x * 128, m0 = blockIdx.y * 128;
    f32x4 acc[4][4]; zero_acc(acc);
    gemm_core(act, INTER, wd, INTER, INTER, m0, n0, As, Bs, acc);
    int lane = threadIdx.x & 63, wave = threadIdx.x >> 6;
    int quad = lane >> 4, l15 = lane & 15, wm = wave >> 1, wn = wave & 1;
#pragma unroll
    for (int mt = 0; mt < 4; ++mt)
#pragma unroll
        for (int nt = 0; nt < 4; ++nt)
#pragma unroll
            for (int r = 0; r < 4; ++r) {
                int gm = m0 + wm*64 + mt*16 + quad*4 + r;
                int gn = n0 + gncol(wn, nt, l15);
                size_t idx = (size_t)gm*HIDDEN + gn;
                out[idx] = acc[mt][nt][r] + h[idx];
            }
}

// ---------------------------------------------------------------------------
// Flash attention with same-sid + causal mask.
// ---------------------------------------------------------------------------
__global__ __launch_bounds__(256) void k_attn(
        const __bf16* __restrict__ qb,   // [2048,2048] rope'd, pre-scaled
        const __bf16* __restrict__ kb,   // [2048,1024] rope'd
        const __bf16* __restrict__ vt,   // [1024][2048] transposed
        const int* __restrict__ sid,     // [2048]
        __bf16* __restrict__ o) {        // [2048,2048]
    __shared__ int    sid_lds[SEQ];        // 8KB
    __shared__ __bf16 Kt[64*128];          // 16KB [key][d]
    __shared__ __bf16 Vt[128*64];          // 16KB [d][key]
    __shared__ __bf16 Pl[4*1024];          // 8KB, per-wave 16x64

    int qt = blockIdx.x;          // 0..31
    int h  = blockIdx.y;          // 0..15
    int hk = h >> 1;              // GQA: rep=2
    int tid = threadIdx.x, wave = tid >> 6, lane = tid & 63;
    int quad = lane >> 4, l15 = lane & 15;
    int q0 = qt * 64;
    int qrow_base = q0 + wave * 16;

    for (int i = tid; i < SEQ; i += 256) sid_lds[i] = sid[i];

    bf16x8 qfrag[4];
#pragma unroll
    for (int seg = 0; seg < 4; ++seg)
        qfrag[seg] = *(const bf16x8*)(qb + (size_t)(qrow_base + l15)*2048
                                         + h*128 + seg*32 + quad*8);
    __syncthreads();
    int sq[4];
#pragma unroll
    for (int r = 0; r < 4; ++r) sq[r] = sid_lds[qrow_base + quad*4 + r];

    float m_i[4], l_i[4];
    f32x4 oacc[8];
#pragma unroll
    for (int r = 0; r < 4; ++r) { m_i[r] = -INFINITY; l_i[r] = 0.f; }
#pragma unroll
    for (int n = 0; n < 8; ++n) {
        oacc[n][0] = 0.f; oacc[n][1] = 0.f; oacc[n][2] = 0.f; oacc[n][3] = 0.f;
    }

    for (int kt = 0; kt <= qt; ++kt) {
        int k0 = kt * 64;
        __syncthreads();
#pragma unroll
        for (int t2 = 0; t2 < 4; ++t2) {
            int c   = wave*4 + t2;
            int row = c*4 + (lane >> 4);
            g2l16(kb + (size_t)(k0 + row)*1024 + hk*128 + (lane & 15)*8,
                  (char*)Kt + c*1024 + lane*16);
        }
#pragma unroll
        for (int t2 = 0; t2 < 4; ++t2) {
            int c   = wave*4 + t2;
            int row = c*8 + (lane >> 3);
            g2l16(vt + (size_t)(hk*128 + row)*2048 + k0 + (lane & 7)*8,
                  (char*)Vt + c*1024 + lane*16);
        }
        __syncthreads();

        f32x4 sacc[4];
#pragma unroll
        for (int nt = 0; nt < 4; ++nt) {
            sacc[nt][0]=0.f; sacc[nt][1]=0.f; sacc[nt][2]=0.f; sacc[nt][3]=0.f;
        }
#pragma unroll
        for (int seg = 0; seg < 4; ++seg)
#pragma unroll
            for (int nt = 0; nt < 4; ++nt) {
                bf16x8 kfr = *(const bf16x8*)((const char*)Kt +
                               (nt*16 + l15)*256 + seg*64 + quad*16);
                sacc[nt] = __builtin_amdgcn_mfma_f32_16x16x32_bf16(
                               qfrag[seg], kfr, sacc[nt], 0, 0, 0);
            }

        int sk[4], kg[4];
#pragma unroll
        for (int nt = 0; nt < 4; ++nt) {
            kg[nt] = k0 + nt*16 + l15;
            sk[nt] = sid_lds[kg[nt]];
        }
        float p[4][4];
#pragma unroll
        for (int r = 0; r < 4; ++r) {
            int qg = qrow_base + quad*4 + r;
            float mx = -INFINITY;
#pragma unroll
            for (int nt = 0; nt < 4; ++nt) {
                bool valid = (kg[nt] <= qg) && (sk[nt] == sq[r]);
                float s = valid ? sacc[nt][r] : -INFINITY;
                p[nt][r] = s;
                mx = fmaxf(mx, s);
            }
            mx = fmaxf(mx, __shfl_xor(mx, 1));
            mx = fmaxf(mx, __shfl_xor(mx, 2));
            mx = fmaxf(mx, __shfl_xor(mx, 4));
            mx = fmaxf(mx, __shfl_xor(mx, 8));
            float mn = fmaxf(m_i[r], mx);
            float alpha = (mn == m_i[r]) ? 1.0f : __expf(m_i[r] - mn);
            float rs = 0.f;
#pragma unroll
            for (int nt = 0; nt < 4; ++nt) {
                float pv = (p[nt][r] == -INFINITY) ? 0.f : __expf(p[nt][r] - mn);
                p[nt][r] = pv;
                rs += pv;
            }
            rs += __shfl_xor(rs, 1);
            rs += __shfl_xor(rs, 2);
            rs += __shfl_xor(rs, 4);
            rs += __shfl_xor(rs, 8);
            l_i[r] = l_i[r] * alpha + rs;
            m_i[r] = mn;
#pragma unroll
            for (int n = 0; n < 8; ++n) oacc[n][r] *= alpha;
        }

#pragma unroll
        for (int nt = 0; nt < 4; ++nt)
#pragma unroll
            for (int r = 0; r < 4; ++r)
                Pl[wave*1024 + (quad*4 + r)*64 + nt*16 + l15] = (__bf16)p[nt][r];
        __syncthreads();

#pragma unroll
        for (int kc = 0; kc < 2; ++kc) {
            bf16x8 pfrag = *(const bf16x8*)((const char*)Pl + wave*2048 +
                             l15*128 + kc*64 + quad*16);
#pragma unroll
            for (int n = 0; n < 8; ++n) {
                bf16x8 vfr = *(const bf16x8*)((const char*)Vt +
                               (n*16 + l15)*128 + kc*64 + quad*16);
                oacc[n] = __builtin_amdgcn_mfma_f32_16x16x32_bf16(
                              pfrag, vfr, oacc[n], 0, 0, 0);
            }
        }
    }

#pragma unroll
    for (int r = 0; r < 4; ++r) {
        float inv = 1.0f / l_i[r];
        size_t base = (size_t)(qrow_base + quad*4 + r)*2048 + h*128 + l15;
#pragma unroll
        for (int n = 0; n < 8; ++n)
            o[base + n*16] = (__bf16)(oacc[n][r] * inv);
    }
}

// ---------------------------------------------------------------------------
// Orchestration
// ---------------------------------------------------------------------------
extern "C" void kernel_launch(void* const* d_in, const int* in_sizes, int n_in,
                              void* d_out, int out_size, void* d_ws, size_t ws_size,
                              hipStream_t stream) {
    (void)in_sizes; (void)n_in; (void)out_size; (void)ws_size;
    const float* hidden = (const float*)d_in[0];
    const int*   sid    = (const int*)d_in[1];
    const int*   pos    = (const int*)d_in[2];
    const float* ln1    = (const float*)d_in[3];
    const float* wq     = (const float*)d_in[4];
    const float* wk     = (const float*)d_in[5];
    const float* wv     = (const float*)d_in[6];
    const float* wo     = (const float*)d_in[7];
    const float* ln2    = (const float*)d_in[8];
    const float* wg     = (const float*)d_in[9];
    const float* wu     = (const float*)d_in[10];
    const float* wd     = (const float*)d_in[11];
    float* out = (float*)d_out;
    char*  ws  = (char*)d_ws;

    // workspace layout, 176 MB total (lifetimes overlapped):
    __bf16* wb   = (__bf16*)(ws);                  // 0..120MB  weights bf16
    __bf16* xb   = (__bf16*)(ws + (120UL << 20));  // 120..128  x (rms1), later ob, later yb
    __bf16* qb   = (__bf16*)(ws + (128UL << 20));  // 128..136  q
    __bf16* kb   = (__bf16*)(ws + (136UL << 20));  // 136..140  k
    __bf16* vtb  = (__bf16*)(ws + (140UL << 20));  // 140..144  v^T
    __bf16* ob   = (__bf16*)(ws + (120UL << 20));  // reuse xb after qkv
    float*  hbuf = (float*) (ws + (128UL << 20));  // 128..144  reuse q/k/v after attn
    __bf16* yb   = (__bf16*)(ws + (120UL << 20));  // reuse ob after oproj
    __bf16* actb = (__bf16*)(ws + (144UL << 20));  // 144..176

    k_cvt<<<30720, 256, 0, stream>>>(wq, wk, wv, wo, wg, wu, wd, wb);
    k_rmsnorm<<<SEQ, 256, 0, stream>>>(hidden, ln1, xb);
    k_gemm_qkv<<<dim3(32, 16), 256, 0, stream>>>(xb, wb, pos, qb, kb, vtb);
    k_attn<<<dim3(32, 16), 256, 0, stream>>>(qb, kb, vtb, sid, ob);
    k_gemm_oproj<<<dim3(16, 16), 256, 0, stream>>>(ob, wb + OFF_WO, hidden, hbuf);
    k_rmsnorm<<<SEQ, 256, 0, stream>>>(hbuf, ln2, yb);
    // MLP: up writes u to actb, then gate reads u and writes silu(g)*u in place
    k_mlp256<<<dim3(32, 8), 512, 0, stream>>>(yb, wb + OFF_WU, actb, 0);
    k_mlp256<<<dim3(32, 8), 512, 0, stream>>>(yb, wb + OFF_WG, actb, 1);
    k_gemm_down<<<dim3(16, 16), 256, 0, stream>>>(actb, wb + OFF_WD, hbuf, out);
}

// Round 3
// 753.135 us; speedup vs baseline: 1.2683x; 1.0915x over previous
//
#include <hip/hip_runtime.h>
#include <hip/hip_bf16.h>
#include <math.h>

#define SEQ    2048
#define HIDDEN 2048
#define INTER  8192
#define NHEADS 16
#define KVH    8
#define HD     128

typedef __bf16 bf16x8 __attribute__((ext_vector_type(8)));
typedef __bf16 bf16x4 __attribute__((ext_vector_type(4)));
typedef float  f32x4  __attribute__((ext_vector_type(4)));

typedef __attribute__((address_space(1))) void* as1v;
typedef __attribute__((address_space(3))) void* as3v;

__device__ __forceinline__ void g2l16(const void* g, void* l) {
    __builtin_amdgcn_global_load_lds((as1v)g, (as3v)l, 16, 0, 0);
}

// weight blob layout (elements) inside ws: wq, wk, wv, wo, wg, wu, wd
#define OFF_WQ 0UL
#define OFF_WK 4194304UL
#define OFF_WV 6291456UL
#define OFF_WO 8388608UL
#define OFF_WG 12582912UL
#define OFF_WU 29360128UL
#define OFF_WD 46137344UL
#define W_TOTAL 62914560UL

// ---------------------------------------------------------------------------
// Weight fp32 -> bf16 conversion (once per launch).  8 elems/thread.
// ---------------------------------------------------------------------------
__global__ __launch_bounds__(256) void k_cvt(
        const float* __restrict__ wq, const float* __restrict__ wk,
        const float* __restrict__ wv, const float* __restrict__ wo,
        const float* __restrict__ wg, const float* __restrict__ wu,
        const float* __restrict__ wd, __bf16* __restrict__ wb) {
    size_t e = ((size_t)blockIdx.x * 256 + threadIdx.x) * 8;
    const float* src; size_t base;
    if      (e < OFF_WK) { src = wq; base = OFF_WQ; }
    else if (e < OFF_WV) { src = wk; base = OFF_WK; }
    else if (e < OFF_WO) { src = wv; base = OFF_WV; }
    else if (e < OFF_WG) { src = wo; base = OFF_WO; }
    else if (e < OFF_WU) { src = wg; base = OFF_WG; }
    else if (e < OFF_WD) { src = wu; base = OFF_WU; }
    else                 { src = wd; base = OFF_WD; }
    const float4* s = (const float4*)(src + (e - base));
    float4 a = s[0], b = s[1];
    bf16x8 o;
    o[0] = (__bf16)a.x; o[1] = (__bf16)a.y; o[2] = (__bf16)a.z; o[3] = (__bf16)a.w;
    o[4] = (__bf16)b.x; o[5] = (__bf16)b.y; o[6] = (__bf16)b.z; o[7] = (__bf16)b.w;
    *(bf16x8*)(wb + e) = o;
}

// ---------------------------------------------------------------------------
// RMSNorm (fp32 in) -> bf16 out.  One block per row of 2048.
// ---------------------------------------------------------------------------
__global__ __launch_bounds__(256) void k_rmsnorm(const float* __restrict__ x,
                                                 const float* __restrict__ w,
                                                 __bf16* __restrict__ out) {
    int row = blockIdx.x;
    int t   = threadIdx.x;
    const float4* xr = (const float4*)(x + (size_t)row * HIDDEN);
    float4 a = xr[t];
    float4 b = xr[t + 256];
    float ss = a.x*a.x + a.y*a.y + a.z*a.z + a.w*a.w
             + b.x*b.x + b.y*b.y + b.z*b.z + b.w*b.w;
#pragma unroll
    for (int d = 32; d > 0; d >>= 1) ss += __shfl_xor(ss, d);
    __shared__ float red[4];
    if ((t & 63) == 0) red[t >> 6] = ss;
    __syncthreads();
    float tot = red[0] + red[1] + red[2] + red[3];
    float r = rsqrtf(tot * (1.0f / (float)HIDDEN) + 1e-6f);
    const float4* wr = (const float4*)w;
    float4 wa = wr[t], wb = wr[t + 256];
    __bf16* o = out + (size_t)row * HIDDEN;
    bf16x4 pa, pb;
    pa[0] = (__bf16)(a.x * r * wa.x);
    pa[1] = (__bf16)(a.y * r * wa.y);
    pa[2] = (__bf16)(a.z * r * wa.z);
    pa[3] = (__bf16)(a.w * r * wa.w);
    pb[0] = (__bf16)(b.x * r * wb.x);
    pb[1] = (__bf16)(b.y * r * wb.y);
    pb[2] = (__bf16)(b.z * r * wb.z);
    pb[3] = (__bf16)(b.w * r * wb.w);
    *(bf16x4*)(o + 4*t)        = pa;
    *(bf16x4*)(o + 4*t + 1024) = pb;
}

// ---------------------------------------------------------------------------
// Pure-bf16 GEMM core, m97 structure (proven): C[128x128] tile.
// ---------------------------------------------------------------------------
__device__ __forceinline__ int gncol(int wn, int nt, int l15) {
    return wn*32 + ((nt & 1) << 4) + ((nt >> 1) << 6) + l15;
}

__device__ __forceinline__ void gemm_core(const __bf16* __restrict__ A, int lda,
                                          const __bf16* __restrict__ B, int ldb,
                                          int K, int m0, int n0,
                                          __bf16* As, __bf16* Bs,
                                          f32x4 acc[4][4]) {
    int tid  = threadIdx.x;
    int wave = tid >> 6;
    int lane = tid & 63;
    int quad = lane >> 4;
    int l15  = lane & 15;
    int wm = wave >> 1, wn = wave & 1;

    int srow = wave*32 + (lane >> 2);
    int scol = (lane & 3) * 8;
    char* adst = (char*)As + wave*2048 + lane*16;
    char* bdst = (char*)Bs + wave*2048 + lane*16;

    for (int k0 = 0; k0 < K; k0 += 32) {
        __syncthreads();
        g2l16(A + (size_t)(m0 + srow)      * lda + k0 + scol, adst);
        g2l16(A + (size_t)(m0 + srow + 16) * lda + k0 + scol, adst + 1024);
        g2l16(B + (size_t)(n0 + srow)      * ldb + k0 + scol, bdst);
        g2l16(B + (size_t)(n0 + srow + 16) * ldb + k0 + scol, bdst + 1024);
        __syncthreads();

        bf16x8 af[4], bfr[4];
#pragma unroll
        for (int mt = 0; mt < 4; ++mt)
            af[mt] = *(const bf16x8*)((const char*)As +
                        (wm*64 + mt*16 + l15)*64 + quad*16);
#pragma unroll
        for (int nt = 0; nt < 4; ++nt) {
            int r = gncol(wn, nt, l15);
            bfr[nt] = *(const bf16x8*)((const char*)Bs + r*64 + quad*16);
        }
#pragma unroll
        for (int mt = 0; mt < 4; ++mt)
#pragma unroll
            for (int nt = 0; nt < 4; ++nt)
                acc[mt][nt] = __builtin_amdgcn_mfma_f32_16x16x32_bf16(
                                  af[mt], bfr[nt], acc[mt][nt], 0, 0, 0);
    }
}

__device__ __forceinline__ void zero_acc(f32x4 acc[4][4]) {
#pragma unroll
    for (int i = 0; i < 4; ++i)
#pragma unroll
        for (int j = 0; j < 4; ++j) {
            acc[i][j][0] = 0.f; acc[i][j][1] = 0.f;
            acc[i][j][2] = 0.f; acc[i][j][3] = 0.f;
        }
}

// ---------------------------------------------------------------------------
// 256x256-tile 8-phase pipelined GEMM core (m201-style, plain HIP).
// 8 waves (2M x 4N), per-wave C = 128x64; BK=64, double-buffered 128 KiB LDS.
// Bank swizzle chunk^=row&7 via pre-swizzled global source + swizzled read.
// Counted vmcnt(4) at phases 4/8 only.  Generalized over row strides ldA/ldB
// (kernels define Ag/Bg/ldA/ldB before using the macros).
// ---------------------------------------------------------------------------
#define MFMA_BF16 __builtin_amdgcn_mfma_f32_16x16x32_bf16
#define VMC asm volatile("s_waitcnt vmcnt(4)" ::: "memory")
#define NOSTMT ((void)0)

#define STAGE_A(BUF, HALF, TILE) do {                                         \
    const __bf16* _s = Ag + (size_t)(m0 + (HALF)*128 + stgRow) * ldA          \
                      + ((size_t)(TILE) << 6) + stgCol;                       \
    char* _d = (char*)smem + (BUF)*65536 + (HALF)*16384 + stgDst;             \
    g2l16(_s, _d);                                                            \
    g2l16(_s + 8*ldA, _d + 1024);                                             \
} while (0)

#define STAGE_B(BUF, HALF, TILE) do {                                         \
    const __bf16* _s = Bg + (size_t)(n0 + (HALF)*128 + stgRow) * ldB          \
                      + ((size_t)(TILE) << 6) + stgCol;                       \
    char* _d = (char*)smem + (BUF)*65536 + 32768 + (HALF)*16384 + stgDst;     \
    g2l16(_s, _d);                                                            \
    g2l16(_s + 8*ldB, _d + 1024);                                             \
} while (0)

#define PHASE(BUF, MH, NH, STAGE_STMT, VMWAIT) do {                           \
    bf16x8 _af[4][2], _bf[2][2];                                              \
    {                                                                         \
        const char* _Ab = (const char*)smem + (BUF)*65536 + (MH)*16384 + aRow;\
        const char* _Bb = (const char*)smem + (BUF)*65536 + 32768             \
                          + (NH)*16384 + bRow;                                \
        _Pragma("unroll")                                                     \
        for (int _m = 0; _m < 4; ++_m) {                                      \
            _af[_m][0] = *(const bf16x8*)(_Ab + _m*2048 + off0);              \
            _af[_m][1] = *(const bf16x8*)(_Ab + _m*2048 + (off0^64));         \
        }                                                                     \
        _Pragma("unroll")                                                     \
        for (int _n = 0; _n < 2; ++_n) {                                      \
            _bf[_n][0] = *(const bf16x8*)(_Bb + _n*2048 + off0);              \
            _bf[_n][1] = *(const bf16x8*)(_Bb + _n*2048 + (off0^64));         \
        }                                                                     \
    }                                                                         \
    STAGE_STMT;                                                               \
    VMWAIT;                                                                   \
    asm volatile("" ::: "memory");                                            \
    __builtin_amdgcn_s_barrier();                                             \
    asm volatile("" ::: "memory");                                            \
    __builtin_amdgcn_s_setprio(1);                                            \
    _Pragma("unroll")                                                         \
    for (int _m = 0; _m < 4; ++_m)                                            \
        _Pragma("unroll")                                                     \
        for (int _n = 0; _n < 2; ++_n) {                                      \
            acc[MH][NH][_m][_n] = MFMA_BF16(_af[_m][0], _bf[_n][0],           \
                                            acc[MH][NH][_m][_n], 0, 0, 0);    \
            acc[MH][NH][_m][_n] = MFMA_BF16(_af[_m][1], _bf[_n][1],           \
                                            acc[MH][NH][_m][_n], 0, 0, 0);    \
        }                                                                     \
    __builtin_amdgcn_s_setprio(0);                                            \
    asm volatile("" ::: "memory");                                            \
    __builtin_amdgcn_s_barrier();                                             \
    asm volatile("" ::: "memory");                                            \
} while (0)

#define P256_PRE                                                              \
    int tid  = threadIdx.x;                                                   \
    int wave = tid >> 6, lane = tid & 63;                                     \
    int wm = wave >> 2, wn = wave & 3;                                        \
    int quad = lane >> 4, l15 = lane & 15;                                    \
    int cx   = l15 & 7;                                                       \
    int off0 = (quad ^ cx) << 4;                                              \
    int aRow = (wm*64 + l15) << 7;                                            \
    int bRow = (wn*32 + l15) << 7;                                            \
    int stgRow = wave*16 + (lane >> 3);                                       \
    int stgCol = ((lane & 7) ^ (lane >> 3)) << 3;                             \
    int stgDst = wave*2048 + lane*16;                                         \
    f32x4 acc[2][2][4][2];                                                    \
    _Pragma("unroll")                                                         \
    for (int _a = 0; _a < 2; ++_a)                                            \
        _Pragma("unroll")                                                     \
        for (int _b = 0; _b < 2; ++_b)                                        \
            _Pragma("unroll")                                                 \
            for (int _c = 0; _c < 4; ++_c)                                    \
                _Pragma("unroll")                                             \
                for (int _d = 0; _d < 2; ++_d) {                              \
                    acc[_a][_b][_c][_d][0] = 0.f; acc[_a][_b][_c][_d][1] = 0.f;\
                    acc[_a][_b][_c][_d][2] = 0.f; acc[_a][_b][_c][_d][3] = 0.f;\
                }

#define P256_LOOP(NT)                                                         \
    STAGE_A(0, 0, 0); STAGE_B(0, 0, 0);                                       \
    STAGE_A(0, 1, 0); STAGE_B(0, 1, 0);                                       \
    STAGE_A(1, 0, 1); STAGE_B(1, 0, 1);                                       \
    VMC;                                                                      \
    asm volatile("" ::: "memory");                                            \
    __builtin_amdgcn_s_barrier();                                             \
    asm volatile("" ::: "memory");                                            \
    for (int i = 0; i < (NT)/2; ++i) {                                        \
        int t1 = (2*i + 1) & ((NT)-1);                                        \
        int t2 = (2*i + 2) & ((NT)-1);                                        \
        int t3 = (2*i + 3) & ((NT)-1);                                        \
        PHASE(0, 0, 0, STAGE_A(1, 1, t1), NOSTMT);                            \
        PHASE(0, 0, 1, STAGE_B(1, 1, t1), NOSTMT);                            \
        PHASE(0, 1, 0, STAGE_A(0, 0, t2), NOSTMT);                            \
        PHASE(0, 1, 1, STAGE_B(0, 0, t2), VMC);                               \
        PHASE(1, 0, 0, STAGE_A(0, 1, t2), NOSTMT);                            \
        PHASE(1, 0, 1, STAGE_B(0, 1, t2), NOSTMT);                            \
        PHASE(1, 1, 0, STAGE_A(1, 0, t3), NOSTMT);                            \
        PHASE(1, 1, 1, STAGE_B(1, 0, t3), VMC);                               \
    }

// mode 0: outb = A@W^T (bf16).  mode 1: outb = silu(A@W^T) * outb (in place).
__global__ __launch_bounds__(512, 2) void k_mlp256(
        const __bf16* __restrict__ Aptr,   // [2048][2048] bf16
        const __bf16* __restrict__ Bptr,   // [8192][2048] bf16
        __bf16* __restrict__ outb,         // [2048][8192] bf16
        int mode) {
    __shared__ char smem[131072];

    // XCD-aware swizzle: 256 wgs, 8 XCDs, each XCD owns one 256-row m-stripe
    int flat = blockIdx.y * 32 + blockIdx.x;          // grid = (32, 8)
    int swz  = (flat & 7) * 32 + (flat >> 3);
    int m0 = (swz >> 5) * 256;
    int n0 = (swz & 31) * 256;
    const __bf16* Ag = Aptr;
    const __bf16* Bg = Bptr;
    const int ldA = 2048, ldB = 2048;

    P256_PRE;
    P256_LOOP(32);

    // epilogue
    int gm0 = m0 + wm*64 + quad*4;
    int gn0 = n0 + wn*32 + l15;
    if (mode == 0) {
#pragma unroll
        for (int mh = 0; mh < 2; ++mh)
#pragma unroll
            for (int nh = 0; nh < 2; ++nh)
#pragma unroll
                for (int mt2 = 0; mt2 < 4; ++mt2)
#pragma unroll
                    for (int nt2 = 0; nt2 < 2; ++nt2)
#pragma unroll
                        for (int r = 0; r < 4; ++r) {
                            int gm = gm0 + mh*128 + mt2*16 + r;
                            int gn = gn0 + nh*128 + nt2*16;
                            outb[(size_t)gm*INTER + gn] =
                                (__bf16)acc[mh][nh][mt2][nt2][r];
                        }
    } else {
#pragma unroll
        for (int mh = 0; mh < 2; ++mh)
#pragma unroll
            for (int nh = 0; nh < 2; ++nh)
#pragma unroll
                for (int mt2 = 0; mt2 < 4; ++mt2)
#pragma unroll
                    for (int nt2 = 0; nt2 < 2; ++nt2)
#pragma unroll
                        for (int r = 0; r < 4; ++r) {
                            int gm = gm0 + mh*128 + mt2*16 + r;
                            int gn = gn0 + nh*128 + nt2*16;
                            size_t idx = (size_t)gm*INTER + gn;
                            float g = acc[mh][nh][mt2][nt2][r];
                            float u = (float)outb[idx];
                            float s = g / (1.0f + __expf(-g));
                            outb[idx] = (__bf16)(s * u);
                        }
    }
}

// ---------------------------------------------------------------------------
// Split-K down GEMM: partial[kz] = act[:, kz*2048:+2048] @ wd[:, same]^T.
// 256 blocks = 8m x 8n x 4kz, fp32 partials [4][2048][2048].
// ---------------------------------------------------------------------------
__global__ __launch_bounds__(512, 2) void k_dsplit256(
        const __bf16* __restrict__ Aptr,   // act [2048][8192] bf16
        const __bf16* __restrict__ Bptr,   // wd  [2048][8192] bf16
        float* __restrict__ pbuf) {        // [4][2048][2048] fp32
    __shared__ char smem[131072];

    int flat = blockIdx.x;                            // 0..255
    int swz  = (flat & 7) * 32 + (flat >> 3);         // XCD chunking
    int kz = swz >> 6;                                // 0..3
    int m0 = ((swz >> 3) & 7) * 256;
    int n0 = (swz & 7) * 256;
    const __bf16* Ag = Aptr + (size_t)kz * 2048;      // column offset into K
    const __bf16* Bg = Bptr + (size_t)kz * 2048;
    const int ldA = 8192, ldB = 8192;

    P256_PRE;
    P256_LOOP(32);

    float* pout = pbuf + (size_t)kz * 4194304;
    int gm0 = m0 + wm*64 + quad*4;
    int gn0 = n0 + wn*32 + l15;
#pragma unroll
    for (int mh = 0; mh < 2; ++mh)
#pragma unroll
        for (int nh = 0; nh < 2; ++nh)
#pragma unroll
            for (int mt2 = 0; mt2 < 4; ++mt2)
#pragma unroll
                for (int nt2 = 0; nt2 < 2; ++nt2)
#pragma unroll
                    for (int r = 0; r < 4; ++r) {
                        int gm = gm0 + mh*128 + mt2*16 + r;
                        int gn = gn0 + nh*128 + nt2*16;
                        pout[(size_t)gm*HIDDEN + gn] = acc[mh][nh][mt2][nt2][r];
                    }
}

// out = h + p0 + p1 + p2 + p3   (all fp32, 2048x2048)
__global__ __launch_bounds__(256) void k_down_reduce(
        const float* __restrict__ p, const float* __restrict__ h,
        float* __restrict__ out) {
    size_t i = ((size_t)blockIdx.x * 256 + threadIdx.x) * 4;
    float4 a = *(const float4*)(p + i);
    float4 b = *(const float4*)(p + 4194304 + i);
    float4 c = *(const float4*)(p + 8388608 + i);
    float4 d = *(const float4*)(p + 12582912 + i);
    float4 hh = *(const float4*)(h + i);
    float4 o;
    o.x = a.x + b.x + c.x + d.x + hh.x;
    o.y = a.y + b.y + c.y + d.y + hh.y;
    o.z = a.z + b.z + c.z + d.z + hh.z;
    o.w = a.w + b.w + c.w + d.w + hh.w;
    *(float4*)(out + i) = o;
}

// ---------------------------------------------------------------------------
// Fused QKV GEMM + RoPE + V-transpose.
// ---------------------------------------------------------------------------
__global__ __launch_bounds__(256) void k_gemm_qkv(
        const __bf16* __restrict__ x, const __bf16* __restrict__ wb,
        const int* __restrict__ pos_ids,
        __bf16* __restrict__ qb, __bf16* __restrict__ kb,
        __bf16* __restrict__ vtb) {
    __shared__ __bf16 As[128*32];
    __shared__ __bf16 Bs[128*32];
    int bn = blockIdx.x;
    int m0 = blockIdx.y * 128;
    const __bf16* B; int n0; int kind;
    if (bn < 16)      { B = wb + OFF_WQ; n0 = bn*128;      kind = 0; }
    else if (bn < 24) { B = wb + OFF_WK; n0 = (bn-16)*128; kind = 1; }
    else              { B = wb + OFF_WV; n0 = (bn-24)*128; kind = 2; }
    f32x4 acc[4][4]; zero_acc(acc);
    gemm_core(x, HIDDEN, B, HIDDEN, HIDDEN, m0, n0, As, Bs, acc);

    int tid = threadIdx.x, wave = tid >> 6, lane = tid & 63;
    int quad = lane >> 4, l15 = lane & 15, wm = wave >> 1, wn = wave & 1;

    if (kind == 2) {
#pragma unroll
        for (int mt = 0; mt < 4; ++mt)
#pragma unroll
            for (int nt = 0; nt < 4; ++nt) {
                int f  = n0 + gncol(wn, nt, l15);
                int gm = m0 + wm*64 + mt*16 + quad*4;
                bf16x4 vv;
                vv[0] = (__bf16)acc[mt][nt][0];
                vv[1] = (__bf16)acc[mt][nt][1];
                vv[2] = (__bf16)acc[mt][nt][2];
                vv[3] = (__bf16)acc[mt][nt][3];
                *(bf16x4*)(vtb + (size_t)f*2048 + gm) = vv;
            }
    } else {
        __bf16* out = (kind == 0) ? qb : kb;
        int ldc     = (kind == 0) ? 2048 : 1024;
        float scale = (kind == 0) ? 0.08838834764831845f : 1.0f;
        int i0 = wn*32 + l15;
        const float LN1E4_64 = 0.14391156831212787f;
        float f0 = __expf(-LN1E4_64 * (float)i0);
        float f1 = __expf(-LN1E4_64 * (float)(i0 + 16));
#pragma unroll
        for (int mt = 0; mt < 4; ++mt)
#pragma unroll
            for (int r = 0; r < 4; ++r) {
                int gm = m0 + wm*64 + mt*16 + quad*4 + r;
                float pos = (float)pos_ids[gm];
                float s0, c0, s1, c1;
                __sincosf(pos * f0, &s0, &c0);
                __sincosf(pos * f1, &s1, &c1);
                float a0 = acc[mt][0][r], a1 = acc[mt][1][r];
                float a2 = acc[mt][2][r], a3 = acc[mt][3][r];
                size_t rowb = (size_t)gm * ldc + n0 + wn*32 + l15;
                out[rowb]      = (__bf16)((a0*c0 - a2*s0) * scale);
                out[rowb + 16] = (__bf16)((a1*c1 - a3*s1) * scale);
                out[rowb + 64] = (__bf16)((a2*c0 + a0*s0) * scale);
                out[rowb + 80] = (__bf16)((a3*c1 + a1*s1) * scale);
            }
    }
}

// ---------------------------------------------------------------------------
// O-projection + residual: h = resid + o @ wo^T  (fp32 out)
// ---------------------------------------------------------------------------
__global__ __launch_bounds__(256) void k_gemm_oproj(
        const __bf16* __restrict__ ob, const __bf16* __restrict__ wo,
        const float* __restrict__ resid, float* __restrict__ h) {
    __shared__ __bf16 As[128*32];
    __shared__ __bf16 Bs[128*32];
    int n0 = blockIdx.x * 128, m0 = blockIdx.y * 128;
    f32x4 acc[4][4]; zero_acc(acc);
    gemm_core(ob, HIDDEN, wo, HIDDEN, HIDDEN, m0, n0, As, Bs, acc);
    int lane = threadIdx.x & 63, wave = threadIdx.x >> 6;
    int quad = lane >> 4, l15 = lane & 15, wm = wave >> 1, wn = wave & 1;
#pragma unroll
    for (int mt = 0; mt < 4; ++mt)
#pragma unroll
        for (int nt = 0; nt < 4; ++nt)
#pragma unroll
            for (int r = 0; r < 4; ++r) {
                int gm = m0 + wm*64 + mt*16 + quad*4 + r;
                int gn = n0 + gncol(wn, nt, l15);
                size_t idx = (size_t)gm*HIDDEN + gn;
                h[idx] = acc[mt][nt][r] + resid[idx];
            }
}

// ---------------------------------------------------------------------------
// Down GEMM + residual (fallback when workspace too small for split-K)
// ---------------------------------------------------------------------------
__global__ __launch_bounds__(256) void k_gemm_down(
        const __bf16* __restrict__ act, const __bf16* __restrict__ wd,
        const float* __restrict__ h, float* __restrict__ out) {
    __shared__ __bf16 As[128*32];
    __shared__ __bf16 Bs[128*32];
    int n0 = blockIdx.x * 128, m0 = blockIdx.y * 128;
    f32x4 acc[4][4]; zero_acc(acc);
    gemm_core(act, INTER, wd, INTER, INTER, m0, n0, As, Bs, acc);
    int lane = threadIdx.x & 63, wave = threadIdx.x >> 6;
    int quad = lane >> 4, l15 = lane & 15, wm = wave >> 1, wn = wave & 1;
#pragma unroll
    for (int mt = 0; mt < 4; ++mt)
#pragma unroll
        for (int nt = 0; nt < 4; ++nt)
#pragma unroll
            for (int r = 0; r < 4; ++r) {
                int gm = m0 + wm*64 + mt*16 + quad*4 + r;
                int gn = n0 + gncol(wn, nt, l15);
                size_t idx = (size_t)gm*HIDDEN + gn;
                out[idx] = acc[mt][nt][r] + h[idx];
            }
}

// ---------------------------------------------------------------------------
// Flash attention with same-sid + causal mask.
// ---------------------------------------------------------------------------
__global__ __launch_bounds__(256) void k_attn(
        const __bf16* __restrict__ qb,   // [2048,2048] rope'd, pre-scaled
        const __bf16* __restrict__ kb,   // [2048,1024] rope'd
        const __bf16* __restrict__ vt,   // [1024][2048] transposed
        const int* __restrict__ sid,     // [2048]
        __bf16* __restrict__ o) {        // [2048,2048]
    __shared__ int    sid_lds[SEQ];        // 8KB
    __shared__ __bf16 Kt[64*128];          // 16KB [key][d]
    __shared__ __bf16 Vt[128*64];          // 16KB [d][key]
    __shared__ __bf16 Pl[4*1024];          // 8KB, per-wave 16x64

    int qt = blockIdx.x;          // 0..31
    int h  = blockIdx.y;          // 0..15
    int hk = h >> 1;              // GQA: rep=2
    int tid = threadIdx.x, wave = tid >> 6, lane = tid & 63;
    int quad = lane >> 4, l15 = lane & 15;
    int q0 = qt * 64;
    int qrow_base = q0 + wave * 16;

    for (int i = tid; i < SEQ; i += 256) sid_lds[i] = sid[i];

    bf16x8 qfrag[4];
#pragma unroll
    for (int seg = 0; seg < 4; ++seg)
        qfrag[seg] = *(const bf16x8*)(qb + (size_t)(qrow_base + l15)*2048
                                         + h*128 + seg*32 + quad*8);
    __syncthreads();
    int sq[4];
#pragma unroll
    for (int r = 0; r < 4; ++r) sq[r] = sid_lds[qrow_base + quad*4 + r];

    float m_i[4], l_i[4];
    f32x4 oacc[8];
#pragma unroll
    for (int r = 0; r < 4; ++r) { m_i[r] = -INFINITY; l_i[r] = 0.f; }
#pragma unroll
    for (int n = 0; n < 8; ++n) {
        oacc[n][0] = 0.f; oacc[n][1] = 0.f; oacc[n][2] = 0.f; oacc[n][3] = 0.f;
    }

    for (int kt = 0; kt <= qt; ++kt) {
        int k0 = kt * 64;
        __syncthreads();
#pragma unroll
        for (int t2 = 0; t2 < 4; ++t2) {
            int c   = wave*4 + t2;
            int row = c*4 + (lane >> 4);
            g2l16(kb + (size_t)(k0 + row)*1024 + hk*128 + (lane & 15)*8,
                  (char*)Kt + c*1024 + lane*16);
        }
#pragma unroll
        for (int t2 = 0; t2 < 4; ++t2) {
            int c   = wave*4 + t2;
            int row = c*8 + (lane >> 3);
            g2l16(vt + (size_t)(hk*128 + row)*2048 + k0 + (lane & 7)*8,
                  (char*)Vt + c*1024 + lane*16);
        }
        __syncthreads();

        f32x4 sacc[4];
#pragma unroll
        for (int nt = 0; nt < 4; ++nt) {
            sacc[nt][0]=0.f; sacc[nt][1]=0.f; sacc[nt][2]=0.f; sacc[nt][3]=0.f;
        }
#pragma unroll
        for (int seg = 0; seg < 4; ++seg)
#pragma unroll
            for (int nt = 0; nt < 4; ++nt) {
                bf16x8 kfr = *(const bf16x8*)((const char*)Kt +
                               (nt*16 + l15)*256 + seg*64 + quad*16);
                sacc[nt] = __builtin_amdgcn_mfma_f32_16x16x32_bf16(
                               qfrag[seg], kfr, sacc[nt], 0, 0, 0);
            }

        int sk[4], kg[4];
#pragma unroll
        for (int nt = 0; nt < 4; ++nt) {
            kg[nt] = k0 + nt*16 + l15;
            sk[nt] = sid_lds[kg[nt]];
        }
        float p[4][4];
#pragma unroll
        for (int r = 0; r < 4; ++r) {
            int qg = qrow_base + quad*4 + r;
            float mx = -INFINITY;
#pragma unroll
            for (int nt = 0; nt < 4; ++nt) {
                bool valid = (kg[nt] <= qg) && (sk[nt] == sq[r]);
                float s = valid ? sacc[nt][r] : -INFINITY;
                p[nt][r] = s;
                mx = fmaxf(mx, s);
            }
            mx = fmaxf(mx, __shfl_xor(mx, 1));
            mx = fmaxf(mx, __shfl_xor(mx, 2));
            mx = fmaxf(mx, __shfl_xor(mx, 4));
            mx = fmaxf(mx, __shfl_xor(mx, 8));
            float mn = fmaxf(m_i[r], mx);
            float alpha = (mn == m_i[r]) ? 1.0f : __expf(m_i[r] - mn);
            float rs = 0.f;
#pragma unroll
            for (int nt = 0; nt < 4; ++nt) {
                float pv = (p[nt][r] == -INFINITY) ? 0.f : __expf(p[nt][r] - mn);
                p[nt][r] = pv;
                rs += pv;
            }
            rs += __shfl_xor(rs, 1);
            rs += __shfl_xor(rs, 2);
            rs += __shfl_xor(rs, 4);
            rs += __shfl_xor(rs, 8);
            l_i[r] = l_i[r] * alpha + rs;
            m_i[r] = mn;
#pragma unroll
            for (int n = 0; n < 8; ++n) oacc[n][r] *= alpha;
        }

#pragma unroll
        for (int nt = 0; nt < 4; ++nt)
#pragma unroll
            for (int r = 0; r < 4; ++r)
                Pl[wave*1024 + (quad*4 + r)*64 + nt*16 + l15] = (__bf16)p[nt][r];
        __syncthreads();

#pragma unroll
        for (int kc = 0; kc < 2; ++kc) {
            bf16x8 pfrag = *(const bf16x8*)((const char*)Pl + wave*2048 +
                             l15*128 + kc*64 + quad*16);
#pragma unroll
            for (int n = 0; n < 8; ++n) {
                bf16x8 vfr = *(const bf16x8*)((const char*)Vt +
                               (n*16 + l15)*128 + kc*64 + quad*16);
                oacc[n] = __builtin_amdgcn_mfma_f32_16x16x32_bf16(
                              pfrag, vfr, oacc[n], 0, 0, 0);
            }
        }
    }

#pragma unroll
    for (int r = 0; r < 4; ++r) {
        float inv = 1.0f / l_i[r];
        size_t base = (size_t)(qrow_base + quad*4 + r)*2048 + h*128 + l15;
#pragma unroll
        for (int n = 0; n < 8; ++n)
            o[base + n*16] = (__bf16)(oacc[n][r] * inv);
    }
}

// ---------------------------------------------------------------------------
// Orchestration
// ---------------------------------------------------------------------------
extern "C" void kernel_launch(void* const* d_in, const int* in_sizes, int n_in,
                              void* d_out, int out_size, void* d_ws, size_t ws_size,
                              hipStream_t stream) {
    (void)in_sizes; (void)n_in; (void)out_size;
    const float* hidden = (const float*)d_in[0];
    const int*   sid    = (const int*)d_in[1];
    const int*   pos    = (const int*)d_in[2];
    const float* ln1    = (const float*)d_in[3];
    const float* wq     = (const float*)d_in[4];
    const float* wk     = (const float*)d_in[5];
    const float* wv     = (const float*)d_in[6];
    const float* wo     = (const float*)d_in[7];
    const float* ln2    = (const float*)d_in[8];
    const float* wg     = (const float*)d_in[9];
    const float* wu     = (const float*)d_in[10];
    const float* wd     = (const float*)d_in[11];
    float* out = (float*)d_out;
    char*  ws  = (char*)d_ws;

    // workspace layout (lifetimes overlapped):
    __bf16* wb   = (__bf16*)(ws);                  // 0..120MB  weights bf16
    __bf16* xb   = (__bf16*)(ws + (120UL << 20));  // 120..128  x (rms1), later ob, later yb
    __bf16* qb   = (__bf16*)(ws + (128UL << 20));  // 128..136  q
    __bf16* kb   = (__bf16*)(ws + (136UL << 20));  // 136..140  k
    __bf16* vtb  = (__bf16*)(ws + (140UL << 20));  // 140..144  v^T
    __bf16* ob   = (__bf16*)(ws + (120UL << 20));  // reuse xb after qkv
    float*  hbuf = (float*) (ws + (128UL << 20));  // 128..144  reuse q/k/v after attn
    __bf16* yb   = (__bf16*)(ws + (120UL << 20));  // reuse ob after oproj
    __bf16* actb = (__bf16*)(ws + (144UL << 20));  // 144..176
    float*  pbuf = (float*) (ws + (176UL << 20));  // 176..240  split-K partials

    k_cvt<<<30720, 256, 0, stream>>>(wq, wk, wv, wo, wg, wu, wd, wb);
    k_rmsnorm<<<SEQ, 256, 0, stream>>>(hidden, ln1, xb);
    k_gemm_qkv<<<dim3(32, 16), 256, 0, stream>>>(xb, wb, pos, qb, kb, vtb);
    k_attn<<<dim3(32, 16), 256, 0, stream>>>(qb, kb, vtb, sid, ob);
    k_gemm_oproj<<<dim3(16, 16), 256, 0, stream>>>(ob, wb + OFF_WO, hidden, hbuf);
    k_rmsnorm<<<SEQ, 256, 0, stream>>>(hbuf, ln2, yb);
    // MLP: up writes u to actb, then gate reads u and writes silu(g)*u in place
    k_mlp256<<<dim3(32, 8), 512, 0, stream>>>(yb, wb + OFF_WU, actb, 0);
    k_mlp256<<<dim3(32, 8), 512, 0, stream>>>(yb, wb + OFF_WG, actb, 1);
    if (ws_size >= (240UL << 20)) {
        k_dsplit256<<<256, 512, 0, stream>>>(actb, wb + OFF_WD, pbuf);
        k_down_reduce<<<4096, 256, 0, stream>>>(pbuf, hbuf, out);
    } else {
        k_gemm_down<<<dim3(16, 16), 256, 0, stream>>>(actb, wb + OFF_WD, hbuf, out);
    }
}

// Round 4
// 687.570 us; speedup vs baseline: 1.3892x; 1.0954x over previous
//
#include <hip/hip_runtime.h>
#include <hip/hip_bf16.h>
#include <math.h>

#define SEQ    2048
#define HIDDEN 2048
#define INTER  8192
#define NHEADS 16
#define KVH    8
#define HD     128

typedef __bf16 bf16x8 __attribute__((ext_vector_type(8)));
typedef __bf16 bf16x4 __attribute__((ext_vector_type(4)));
typedef float  f32x4  __attribute__((ext_vector_type(4)));

typedef __attribute__((address_space(1))) void* as1v;
typedef __attribute__((address_space(3))) void* as3v;

__device__ __forceinline__ void g2l16(const void* g, void* l) {
    __builtin_amdgcn_global_load_lds((as1v)g, (as3v)l, 16, 0, 0);
}

// weight blob layout (elements) inside ws: wq, wk, wv, wo, wg, wu, wd
#define OFF_WQ 0UL
#define OFF_WK 4194304UL
#define OFF_WV 6291456UL
#define OFF_WO 8388608UL
#define OFF_WG 12582912UL
#define OFF_WU 29360128UL
#define OFF_WD 46137344UL
#define W_TOTAL 62914560UL

// ---------------------------------------------------------------------------
// Weight fp32 -> bf16 conversion (once per launch).  8 elems/thread.
// ---------------------------------------------------------------------------
__global__ __launch_bounds__(256) void k_cvt(
        const float* __restrict__ wq, const float* __restrict__ wk,
        const float* __restrict__ wv, const float* __restrict__ wo,
        const float* __restrict__ wg, const float* __restrict__ wu,
        const float* __restrict__ wd, __bf16* __restrict__ wb) {
    size_t e = ((size_t)blockIdx.x * 256 + threadIdx.x) * 8;
    const float* src; size_t base;
    if      (e < OFF_WK) { src = wq; base = OFF_WQ; }
    else if (e < OFF_WV) { src = wk; base = OFF_WK; }
    else if (e < OFF_WO) { src = wv; base = OFF_WV; }
    else if (e < OFF_WG) { src = wo; base = OFF_WO; }
    else if (e < OFF_WU) { src = wg; base = OFF_WG; }
    else if (e < OFF_WD) { src = wu; base = OFF_WU; }
    else                 { src = wd; base = OFF_WD; }
    const float4* s = (const float4*)(src + (e - base));
    float4 a = s[0], b = s[1];
    bf16x8 o;
    o[0] = (__bf16)a.x; o[1] = (__bf16)a.y; o[2] = (__bf16)a.z; o[3] = (__bf16)a.w;
    o[4] = (__bf16)b.x; o[5] = (__bf16)b.y; o[6] = (__bf16)b.z; o[7] = (__bf16)b.w;
    *(bf16x8*)(wb + e) = o;
}

// ---------------------------------------------------------------------------
// RMSNorm (fp32 in) -> bf16 out.  One block per row of 2048.
// ---------------------------------------------------------------------------
__global__ __launch_bounds__(256) void k_rmsnorm(const float* __restrict__ x,
                                                 const float* __restrict__ w,
                                                 __bf16* __restrict__ out) {
    int row = blockIdx.x;
    int t   = threadIdx.x;
    const float4* xr = (const float4*)(x + (size_t)row * HIDDEN);
    float4 a = xr[t];
    float4 b = xr[t + 256];
    float ss = a.x*a.x + a.y*a.y + a.z*a.z + a.w*a.w
             + b.x*b.x + b.y*b.y + b.z*b.z + b.w*b.w;
#pragma unroll
    for (int d = 32; d > 0; d >>= 1) ss += __shfl_xor(ss, d);
    __shared__ float red[4];
    if ((t & 63) == 0) red[t >> 6] = ss;
    __syncthreads();
    float tot = red[0] + red[1] + red[2] + red[3];
    float r = rsqrtf(tot * (1.0f / (float)HIDDEN) + 1e-6f);
    const float4* wr = (const float4*)w;
    float4 wa = wr[t], wb = wr[t + 256];
    __bf16* o = out + (size_t)row * HIDDEN;
    bf16x4 pa, pb;
    pa[0] = (__bf16)(a.x * r * wa.x);
    pa[1] = (__bf16)(a.y * r * wa.y);
    pa[2] = (__bf16)(a.z * r * wa.z);
    pa[3] = (__bf16)(a.w * r * wa.w);
    pb[0] = (__bf16)(b.x * r * wb.x);
    pb[1] = (__bf16)(b.y * r * wb.y);
    pb[2] = (__bf16)(b.z * r * wb.z);
    pb[3] = (__bf16)(b.w * r * wb.w);
    *(bf16x4*)(o + 4*t)        = pa;
    *(bf16x4*)(o + 4*t + 1024) = pb;
}

// ---------------------------------------------------------------------------
// Pure-bf16 GEMM core, m97 structure (proven): C[128x128] tile.
// ---------------------------------------------------------------------------
__device__ __forceinline__ int gncol(int wn, int nt, int l15) {
    return wn*32 + ((nt & 1) << 4) + ((nt >> 1) << 6) + l15;
}

__device__ __forceinline__ void gemm_core(const __bf16* __restrict__ A, int lda,
                                          const __bf16* __restrict__ B, int ldb,
                                          int K, int m0, int n0,
                                          __bf16* As, __bf16* Bs,
                                          f32x4 acc[4][4]) {
    int tid  = threadIdx.x;
    int wave = tid >> 6;
    int lane = tid & 63;
    int quad = lane >> 4;
    int l15  = lane & 15;
    int wm = wave >> 1, wn = wave & 1;

    int srow = wave*32 + (lane >> 2);
    int scol = (lane & 3) * 8;
    char* adst = (char*)As + wave*2048 + lane*16;
    char* bdst = (char*)Bs + wave*2048 + lane*16;

    for (int k0 = 0; k0 < K; k0 += 32) {
        __syncthreads();
        g2l16(A + (size_t)(m0 + srow)      * lda + k0 + scol, adst);
        g2l16(A + (size_t)(m0 + srow + 16) * lda + k0 + scol, adst + 1024);
        g2l16(B + (size_t)(n0 + srow)      * ldb + k0 + scol, bdst);
        g2l16(B + (size_t)(n0 + srow + 16) * ldb + k0 + scol, bdst + 1024);
        __syncthreads();

        bf16x8 af[4], bfr[4];
#pragma unroll
        for (int mt = 0; mt < 4; ++mt)
            af[mt] = *(const bf16x8*)((const char*)As +
                        (wm*64 + mt*16 + l15)*64 + quad*16);
#pragma unroll
        for (int nt = 0; nt < 4; ++nt) {
            int r = gncol(wn, nt, l15);
            bfr[nt] = *(const bf16x8*)((const char*)Bs + r*64 + quad*16);
        }
#pragma unroll
        for (int mt = 0; mt < 4; ++mt)
#pragma unroll
            for (int nt = 0; nt < 4; ++nt)
                acc[mt][nt] = __builtin_amdgcn_mfma_f32_16x16x32_bf16(
                                  af[mt], bfr[nt], acc[mt][nt], 0, 0, 0);
    }
}

__device__ __forceinline__ void zero_acc(f32x4 acc[4][4]) {
#pragma unroll
    for (int i = 0; i < 4; ++i)
#pragma unroll
        for (int j = 0; j < 4; ++j) {
            acc[i][j][0] = 0.f; acc[i][j][1] = 0.f;
            acc[i][j][2] = 0.f; acc[i][j][3] = 0.f;
        }
}

// ---------------------------------------------------------------------------
// 256x256-tile 8-phase pipelined GEMM core (m201-style, plain HIP).
// 8 waves (2M x 4N), per-wave C = 128x64; BK=64, double-buffered 128 KiB LDS.
// Bank swizzle chunk^=row&7 via pre-swizzled global source + swizzled read.
// Counted vmcnt(4) at phases 4/8 only.  Generalized over row strides ldA/ldB
// (kernels define Ag/Bg/ldA/ldB before using the macros).
// ---------------------------------------------------------------------------
#define MFMA_BF16 __builtin_amdgcn_mfma_f32_16x16x32_bf16
#define VMC asm volatile("s_waitcnt vmcnt(4)" ::: "memory")
#define NOSTMT ((void)0)

#define STAGE_A(BUF, HALF, TILE) do {                                         \
    const __bf16* _s = Ag + (size_t)(m0 + (HALF)*128 + stgRow) * ldA          \
                      + ((size_t)(TILE) << 6) + stgCol;                       \
    char* _d = (char*)smem + (BUF)*65536 + (HALF)*16384 + stgDst;             \
    g2l16(_s, _d);                                                            \
    g2l16(_s + 8*ldA, _d + 1024);                                             \
} while (0)

#define STAGE_B(BUF, HALF, TILE) do {                                         \
    const __bf16* _s = Bg + (size_t)(n0 + (HALF)*128 + stgRow) * ldB          \
                      + ((size_t)(TILE) << 6) + stgCol;                       \
    char* _d = (char*)smem + (BUF)*65536 + 32768 + (HALF)*16384 + stgDst;     \
    g2l16(_s, _d);                                                            \
    g2l16(_s + 8*ldB, _d + 1024);                                             \
} while (0)

#define PHASE(BUF, MH, NH, STAGE_STMT, VMWAIT) do {                           \
    bf16x8 _af[4][2], _bf[2][2];                                              \
    {                                                                         \
        const char* _Ab = (const char*)smem + (BUF)*65536 + (MH)*16384 + aRow;\
        const char* _Bb = (const char*)smem + (BUF)*65536 + 32768             \
                          + (NH)*16384 + bRow;                                \
        _Pragma("unroll")                                                     \
        for (int _m = 0; _m < 4; ++_m) {                                      \
            _af[_m][0] = *(const bf16x8*)(_Ab + _m*2048 + off0);              \
            _af[_m][1] = *(const bf16x8*)(_Ab + _m*2048 + (off0^64));         \
        }                                                                     \
        _Pragma("unroll")                                                     \
        for (int _n = 0; _n < 2; ++_n) {                                      \
            _bf[_n][0] = *(const bf16x8*)(_Bb + _n*2048 + off0);              \
            _bf[_n][1] = *(const bf16x8*)(_Bb + _n*2048 + (off0^64));         \
        }                                                                     \
    }                                                                         \
    STAGE_STMT;                                                               \
    VMWAIT;                                                                   \
    asm volatile("" ::: "memory");                                            \
    __builtin_amdgcn_s_barrier();                                             \
    asm volatile("" ::: "memory");                                            \
    __builtin_amdgcn_s_setprio(1);                                            \
    _Pragma("unroll")                                                         \
    for (int _m = 0; _m < 4; ++_m)                                            \
        _Pragma("unroll")                                                     \
        for (int _n = 0; _n < 2; ++_n) {                                      \
            acc[MH][NH][_m][_n] = MFMA_BF16(_af[_m][0], _bf[_n][0],           \
                                            acc[MH][NH][_m][_n], 0, 0, 0);    \
            acc[MH][NH][_m][_n] = MFMA_BF16(_af[_m][1], _bf[_n][1],           \
                                            acc[MH][NH][_m][_n], 0, 0, 0);    \
        }                                                                     \
    __builtin_amdgcn_s_setprio(0);                                            \
    asm volatile("" ::: "memory");                                            \
    __builtin_amdgcn_s_barrier();                                             \
    asm volatile("" ::: "memory");                                            \
} while (0)

#define P256_PRE                                                              \
    int tid  = threadIdx.x;                                                   \
    int wave = tid >> 6, lane = tid & 63;                                     \
    int wm = wave >> 2, wn = wave & 3;                                        \
    int quad = lane >> 4, l15 = lane & 15;                                    \
    int cx   = l15 & 7;                                                       \
    int off0 = (quad ^ cx) << 4;                                              \
    int aRow = (wm*64 + l15) << 7;                                            \
    int bRow = (wn*32 + l15) << 7;                                            \
    int stgRow = wave*16 + (lane >> 3);                                       \
    int stgCol = ((lane & 7) ^ (lane >> 3)) << 3;                             \
    int stgDst = wave*2048 + lane*16;                                         \
    f32x4 acc[2][2][4][2];                                                    \
    _Pragma("unroll")                                                         \
    for (int _a = 0; _a < 2; ++_a)                                            \
        _Pragma("unroll")                                                     \
        for (int _b = 0; _b < 2; ++_b)                                        \
            _Pragma("unroll")                                                 \
            for (int _c = 0; _c < 4; ++_c)                                    \
                _Pragma("unroll")                                             \
                for (int _d = 0; _d < 2; ++_d) {                              \
                    acc[_a][_b][_c][_d][0] = 0.f; acc[_a][_b][_c][_d][1] = 0.f;\
                    acc[_a][_b][_c][_d][2] = 0.f; acc[_a][_b][_c][_d][3] = 0.f;\
                }

#define P256_LOOP(NT)                                                         \
    STAGE_A(0, 0, 0); STAGE_B(0, 0, 0);                                       \
    STAGE_A(0, 1, 0); STAGE_B(0, 1, 0);                                       \
    STAGE_A(1, 0, 1); STAGE_B(1, 0, 1);                                       \
    VMC;                                                                      \
    asm volatile("" ::: "memory");                                            \
    __builtin_amdgcn_s_barrier();                                             \
    asm volatile("" ::: "memory");                                            \
    for (int i = 0; i < (NT)/2; ++i) {                                        \
        int t1 = (2*i + 1) & ((NT)-1);                                        \
        int t2 = (2*i + 2) & ((NT)-1);                                        \
        int t3 = (2*i + 3) & ((NT)-1);                                        \
        PHASE(0, 0, 0, STAGE_A(1, 1, t1), NOSTMT);                            \
        PHASE(0, 0, 1, STAGE_B(1, 1, t1), NOSTMT);                            \
        PHASE(0, 1, 0, STAGE_A(0, 0, t2), NOSTMT);                            \
        PHASE(0, 1, 1, STAGE_B(0, 0, t2), VMC);                               \
        PHASE(1, 0, 0, STAGE_A(0, 1, t2), NOSTMT);                            \
        PHASE(1, 0, 1, STAGE_B(0, 1, t2), NOSTMT);                            \
        PHASE(1, 1, 0, STAGE_A(1, 0, t3), NOSTMT);                            \
        PHASE(1, 1, 1, STAGE_B(1, 0, t3), VMC);                               \
    }

// mode 0: outb = A@W^T (bf16).  mode 1: outb = silu(A@W^T) * outb (in place).
__global__ __launch_bounds__(512, 2) void k_mlp256(
        const __bf16* __restrict__ Aptr,   // [2048][2048] bf16
        const __bf16* __restrict__ Bptr,   // [8192][2048] bf16
        __bf16* __restrict__ outb,         // [2048][8192] bf16
        int mode) {
    __shared__ char smem[131072];

    // XCD-aware swizzle: 256 wgs, 8 XCDs, each XCD owns one 256-row m-stripe
    int flat = blockIdx.y * 32 + blockIdx.x;          // grid = (32, 8)
    int swz  = (flat & 7) * 32 + (flat >> 3);
    int m0 = (swz >> 5) * 256;
    int n0 = (swz & 31) * 256;
    const __bf16* Ag = Aptr;
    const __bf16* Bg = Bptr;
    const int ldA = 2048, ldB = 2048;

    P256_PRE;
    P256_LOOP(32);

    // epilogue
    int gm0 = m0 + wm*64 + quad*4;
    int gn0 = n0 + wn*32 + l15;
    if (mode == 0) {
#pragma unroll
        for (int mh = 0; mh < 2; ++mh)
#pragma unroll
            for (int nh = 0; nh < 2; ++nh)
#pragma unroll
                for (int mt2 = 0; mt2 < 4; ++mt2)
#pragma unroll
                    for (int nt2 = 0; nt2 < 2; ++nt2)
#pragma unroll
                        for (int r = 0; r < 4; ++r) {
                            int gm = gm0 + mh*128 + mt2*16 + r;
                            int gn = gn0 + nh*128 + nt2*16;
                            outb[(size_t)gm*INTER + gn] =
                                (__bf16)acc[mh][nh][mt2][nt2][r];
                        }
    } else {
#pragma unroll
        for (int mh = 0; mh < 2; ++mh)
#pragma unroll
            for (int nh = 0; nh < 2; ++nh)
#pragma unroll
                for (int mt2 = 0; mt2 < 4; ++mt2)
#pragma unroll
                    for (int nt2 = 0; nt2 < 2; ++nt2)
#pragma unroll
                        for (int r = 0; r < 4; ++r) {
                            int gm = gm0 + mh*128 + mt2*16 + r;
                            int gn = gn0 + nh*128 + nt2*16;
                            size_t idx = (size_t)gm*INTER + gn;
                            float g = acc[mh][nh][mt2][nt2][r];
                            float u = (float)outb[idx];
                            float s = g / (1.0f + __expf(-g));
                            outb[idx] = (__bf16)(s * u);
                        }
    }
}

// ---------------------------------------------------------------------------
// Split-K down GEMM: partial[kz] = act[:, kz*2048:+2048] @ wd[:, same]^T.
// 256 blocks = 8m x 8n x 4kz, fp32 partials [4][2048][2048].
// ---------------------------------------------------------------------------
__global__ __launch_bounds__(512, 2) void k_dsplit256(
        const __bf16* __restrict__ Aptr,   // act [2048][8192] bf16
        const __bf16* __restrict__ Bptr,   // wd  [2048][8192] bf16
        float* __restrict__ pbuf) {        // [4][2048][2048] fp32
    __shared__ char smem[131072];

    int flat = blockIdx.x;                            // 0..255
    int swz  = (flat & 7) * 32 + (flat >> 3);         // XCD chunking
    int kz = swz >> 6;                                // 0..3
    int m0 = ((swz >> 3) & 7) * 256;
    int n0 = (swz & 7) * 256;
    const __bf16* Ag = Aptr + (size_t)kz * 2048;      // column offset into K
    const __bf16* Bg = Bptr + (size_t)kz * 2048;
    const int ldA = 8192, ldB = 8192;

    P256_PRE;
    P256_LOOP(32);

    float* pout = pbuf + (size_t)kz * 4194304;
    int gm0 = m0 + wm*64 + quad*4;
    int gn0 = n0 + wn*32 + l15;
#pragma unroll
    for (int mh = 0; mh < 2; ++mh)
#pragma unroll
        for (int nh = 0; nh < 2; ++nh)
#pragma unroll
            for (int mt2 = 0; mt2 < 4; ++mt2)
#pragma unroll
                for (int nt2 = 0; nt2 < 2; ++nt2)
#pragma unroll
                    for (int r = 0; r < 4; ++r) {
                        int gm = gm0 + mh*128 + mt2*16 + r;
                        int gn = gn0 + nh*128 + nt2*16;
                        pout[(size_t)gm*HIDDEN + gn] = acc[mh][nh][mt2][nt2][r];
                    }
}

// out = h + p0 + p1 + p2 + p3   (all fp32, 2048x2048)
__global__ __launch_bounds__(256) void k_down_reduce(
        const float* __restrict__ p, const float* __restrict__ h,
        float* __restrict__ out) {
    size_t i = ((size_t)blockIdx.x * 256 + threadIdx.x) * 4;
    float4 a = *(const float4*)(p + i);
    float4 b = *(const float4*)(p + 4194304 + i);
    float4 c = *(const float4*)(p + 8388608 + i);
    float4 d = *(const float4*)(p + 12582912 + i);
    float4 hh = *(const float4*)(h + i);
    float4 o;
    o.x = a.x + b.x + c.x + d.x + hh.x;
    o.y = a.y + b.y + c.y + d.y + hh.y;
    o.z = a.z + b.z + c.z + d.z + hh.z;
    o.w = a.w + b.w + c.w + d.w + hh.w;
    *(float4*)(out + i) = o;
}

// ---------------------------------------------------------------------------
// Fused QKV GEMM + RoPE + V-transpose.
// ---------------------------------------------------------------------------
__global__ __launch_bounds__(256) void k_gemm_qkv(
        const __bf16* __restrict__ x, const __bf16* __restrict__ wb,
        const int* __restrict__ pos_ids,
        __bf16* __restrict__ qb, __bf16* __restrict__ kb,
        __bf16* __restrict__ vtb) {
    __shared__ __bf16 As[128*32];
    __shared__ __bf16 Bs[128*32];
    int bn = blockIdx.x;
    int m0 = blockIdx.y * 128;
    const __bf16* B; int n0; int kind;
    if (bn < 16)      { B = wb + OFF_WQ; n0 = bn*128;      kind = 0; }
    else if (bn < 24) { B = wb + OFF_WK; n0 = (bn-16)*128; kind = 1; }
    else              { B = wb + OFF_WV; n0 = (bn-24)*128; kind = 2; }
    f32x4 acc[4][4]; zero_acc(acc);
    gemm_core(x, HIDDEN, B, HIDDEN, HIDDEN, m0, n0, As, Bs, acc);

    int tid = threadIdx.x, wave = tid >> 6, lane = tid & 63;
    int quad = lane >> 4, l15 = lane & 15, wm = wave >> 1, wn = wave & 1;

    if (kind == 2) {
#pragma unroll
        for (int mt = 0; mt < 4; ++mt)
#pragma unroll
            for (int nt = 0; nt < 4; ++nt) {
                int f  = n0 + gncol(wn, nt, l15);
                int gm = m0 + wm*64 + mt*16 + quad*4;
                bf16x4 vv;
                vv[0] = (__bf16)acc[mt][nt][0];
                vv[1] = (__bf16)acc[mt][nt][1];
                vv[2] = (__bf16)acc[mt][nt][2];
                vv[3] = (__bf16)acc[mt][nt][3];
                *(bf16x4*)(vtb + (size_t)f*2048 + gm) = vv;
            }
    } else {
        __bf16* out = (kind == 0) ? qb : kb;
        int ldc     = (kind == 0) ? 2048 : 1024;
        float scale = (kind == 0) ? 0.08838834764831845f : 1.0f;
        int i0 = wn*32 + l15;
        const float LN1E4_64 = 0.14391156831212787f;
        float f0 = __expf(-LN1E4_64 * (float)i0);
        float f1 = __expf(-LN1E4_64 * (float)(i0 + 16));
#pragma unroll
        for (int mt = 0; mt < 4; ++mt)
#pragma unroll
            for (int r = 0; r < 4; ++r) {
                int gm = m0 + wm*64 + mt*16 + quad*4 + r;
                float pos = (float)pos_ids[gm];
                float s0, c0, s1, c1;
                __sincosf(pos * f0, &s0, &c0);
                __sincosf(pos * f1, &s1, &c1);
                float a0 = acc[mt][0][r], a1 = acc[mt][1][r];
                float a2 = acc[mt][2][r], a3 = acc[mt][3][r];
                size_t rowb = (size_t)gm * ldc + n0 + wn*32 + l15;
                out[rowb]      = (__bf16)((a0*c0 - a2*s0) * scale);
                out[rowb + 16] = (__bf16)((a1*c1 - a3*s1) * scale);
                out[rowb + 64] = (__bf16)((a2*c0 + a0*s0) * scale);
                out[rowb + 80] = (__bf16)((a3*c1 + a1*s1) * scale);
            }
    }
}

// ---------------------------------------------------------------------------
// O-projection + residual: h = resid + o @ wo^T  (fp32 out)
// ---------------------------------------------------------------------------
__global__ __launch_bounds__(256) void k_gemm_oproj(
        const __bf16* __restrict__ ob, const __bf16* __restrict__ wo,
        const float* __restrict__ resid, float* __restrict__ h) {
    __shared__ __bf16 As[128*32];
    __shared__ __bf16 Bs[128*32];
    int n0 = blockIdx.x * 128, m0 = blockIdx.y * 128;
    f32x4 acc[4][4]; zero_acc(acc);
    gemm_core(ob, HIDDEN, wo, HIDDEN, HIDDEN, m0, n0, As, Bs, acc);
    int lane = threadIdx.x & 63, wave = threadIdx.x >> 6;
    int quad = lane >> 4, l15 = lane & 15, wm = wave >> 1, wn = wave & 1;
#pragma unroll
    for (int mt = 0; mt < 4; ++mt)
#pragma unroll
        for (int nt = 0; nt < 4; ++nt)
#pragma unroll
            for (int r = 0; r < 4; ++r) {
                int gm = m0 + wm*64 + mt*16 + quad*4 + r;
                int gn = n0 + gncol(wn, nt, l15);
                size_t idx = (size_t)gm*HIDDEN + gn;
                h[idx] = acc[mt][nt][r] + resid[idx];
            }
}

// ---------------------------------------------------------------------------
// Down GEMM + residual (fallback when workspace too small for split-K)
// ---------------------------------------------------------------------------
__global__ __launch_bounds__(256) void k_gemm_down(
        const __bf16* __restrict__ act, const __bf16* __restrict__ wd,
        const float* __restrict__ h, float* __restrict__ out) {
    __shared__ __bf16 As[128*32];
    __shared__ __bf16 Bs[128*32];
    int n0 = blockIdx.x * 128, m0 = blockIdx.y * 128;
    f32x4 acc[4][4]; zero_acc(acc);
    gemm_core(act, INTER, wd, INTER, INTER, m0, n0, As, Bs, acc);
    int lane = threadIdx.x & 63, wave = threadIdx.x >> 6;
    int quad = lane >> 4, l15 = lane & 15, wm = wave >> 1, wn = wave & 1;
#pragma unroll
    for (int mt = 0; mt < 4; ++mt)
#pragma unroll
        for (int nt = 0; nt < 4; ++nt)
#pragma unroll
            for (int r = 0; r < 4; ++r) {
                int gm = m0 + wm*64 + mt*16 + quad*4 + r;
                int gn = n0 + gncol(wn, nt, l15);
                size_t idx = (size_t)gm*HIDDEN + gn;
                out[idx] = acc[mt][nt][r] + h[idx];
            }
}

// ---------------------------------------------------------------------------
// Flash attention with same-sid + causal mask.
// LDS tiles XOR-swizzled (chunk ^= row&7) to kill the 16-way bank conflicts
// on the strided fragment reads (rows are 256B/128B -> bank bits were
// l15-invariant).  g2l16 dests stay linear; the swizzle is applied by
// permuting the per-lane GLOBAL source chunk (same involution as the read).
// ---------------------------------------------------------------------------
__global__ __launch_bounds__(256) void k_attn(
        const __bf16* __restrict__ qb,   // [2048,2048] rope'd, pre-scaled
        const __bf16* __restrict__ kb,   // [2048,1024] rope'd
        const __bf16* __restrict__ vt,   // [1024][2048] transposed
        const int* __restrict__ sid,     // [2048]
        __bf16* __restrict__ o) {        // [2048,2048]
    __shared__ int    sid_lds[SEQ];        // 8KB
    __shared__ __bf16 Kt[64*128];          // 16KB [key][d], swizzled
    __shared__ __bf16 Vt[128*64];          // 16KB [d][key], swizzled
    __shared__ __bf16 Pl[4*1024];          // 8KB, per-wave 16x64, swizzled

    int qt = blockIdx.x;          // 0..31
    int h  = blockIdx.y;          // 0..15
    int hk = h >> 1;              // GQA: rep=2
    int tid = threadIdx.x, wave = tid >> 6, lane = tid & 63;
    int quad = lane >> 4, l15 = lane & 15;
    int q0 = qt * 64;
    int qrow_base = q0 + wave * 16;
    int sw = l15 & 7;             // read-side swizzle key (row&7 == l15&7)

    for (int i = tid; i < SEQ; i += 256) sid_lds[i] = sid[i];

    bf16x8 qfrag[4];
#pragma unroll
    for (int seg = 0; seg < 4; ++seg)
        qfrag[seg] = *(const bf16x8*)(qb + (size_t)(qrow_base + l15)*2048
                                         + h*128 + seg*32 + quad*8);
    __syncthreads();
    int sq[4];
#pragma unroll
    for (int r = 0; r < 4; ++r) sq[r] = sid_lds[qrow_base + quad*4 + r];

    float m_i[4], l_i[4];
    f32x4 oacc[8];
#pragma unroll
    for (int r = 0; r < 4; ++r) { m_i[r] = -INFINITY; l_i[r] = 0.f; }
#pragma unroll
    for (int n = 0; n < 8; ++n) {
        oacc[n][0] = 0.f; oacc[n][1] = 0.f; oacc[n][2] = 0.f; oacc[n][3] = 0.f;
    }

    // staging source-chunk swizzles (match the read-side XOR):
    // K: row = c*4 + (lane>>4), 16 chunks/row; srcChunkK = (lane&15) ^ (row&7)
    // V: row = c*8 + (lane>>3),  8 chunks/row; srcChunkV = (lane&7)  ^ (row&7)
    int kRowPar = lane >> 4;                 // row&3 contribution (K)
    int vRowPar = lane >> 3;                 // row&7 (V)

    for (int kt = 0; kt <= qt; ++kt) {
        int k0 = kt * 64;
        __syncthreads();
#pragma unroll
        for (int t2 = 0; t2 < 4; ++t2) {
            int c    = wave*4 + t2;
            int row  = c*4 + kRowPar;
            int rk   = ((c & 1) << 2) + kRowPar;       // row&7
            int srcC = (lane & 15) ^ rk;
            g2l16(kb + (size_t)(k0 + row)*1024 + hk*128 + srcC*8,
                  (char*)Kt + c*1024 + lane*16);
        }
#pragma unroll
        for (int t2 = 0; t2 < 4; ++t2) {
            int c    = wave*4 + t2;
            int row  = c*8 + vRowPar;
            int srcC = (lane & 7) ^ vRowPar;           // row&7 == lane>>3
            g2l16(vt + (size_t)(hk*128 + row)*2048 + k0 + srcC*8,
                  (char*)Vt + c*1024 + lane*16);
        }
        __syncthreads();

        f32x4 sacc[4];
#pragma unroll
        for (int nt = 0; nt < 4; ++nt) {
            sacc[nt][0]=0.f; sacc[nt][1]=0.f; sacc[nt][2]=0.f; sacc[nt][3]=0.f;
        }
#pragma unroll
        for (int seg = 0; seg < 4; ++seg)
#pragma unroll
            for (int nt = 0; nt < 4; ++nt) {
                bf16x8 kfr = *(const bf16x8*)((const char*)Kt +
                               (nt*16 + l15)*256 + ((seg*4 + quad) ^ sw)*16);
                sacc[nt] = __builtin_amdgcn_mfma_f32_16x16x32_bf16(
                               qfrag[seg], kfr, sacc[nt], 0, 0, 0);
            }

        int sk[4], kg[4];
#pragma unroll
        for (int nt = 0; nt < 4; ++nt) {
            kg[nt] = k0 + nt*16 + l15;
            sk[nt] = sid_lds[kg[nt]];
        }
        float p[4][4];
#pragma unroll
        for (int r = 0; r < 4; ++r) {
            int qg = qrow_base + quad*4 + r;
            float mx = -INFINITY;
#pragma unroll
            for (int nt = 0; nt < 4; ++nt) {
                bool valid = (kg[nt] <= qg) && (sk[nt] == sq[r]);
                float s = valid ? sacc[nt][r] : -INFINITY;
                p[nt][r] = s;
                mx = fmaxf(mx, s);
            }
            mx = fmaxf(mx, __shfl_xor(mx, 1));
            mx = fmaxf(mx, __shfl_xor(mx, 2));
            mx = fmaxf(mx, __shfl_xor(mx, 4));
            mx = fmaxf(mx, __shfl_xor(mx, 8));
            float mn = fmaxf(m_i[r], mx);
            float alpha = (mn == m_i[r]) ? 1.0f : __expf(m_i[r] - mn);
            float rs = 0.f;
#pragma unroll
            for (int nt = 0; nt < 4; ++nt) {
                float pv = (p[nt][r] == -INFINITY) ? 0.f : __expf(p[nt][r] - mn);
                p[nt][r] = pv;
                rs += pv;
            }
            rs += __shfl_xor(rs, 1);
            rs += __shfl_xor(rs, 2);
            rs += __shfl_xor(rs, 4);
            rs += __shfl_xor(rs, 8);
            l_i[r] = l_i[r] * alpha + rs;
            m_i[r] = mn;
#pragma unroll
            for (int n = 0; n < 8; ++n) oacc[n][r] *= alpha;
        }

        // P write, swizzled: row = quad*4+r (16 rows x 64 cols, 128B rows,
        // 8 chunks/row); chunk = nt*2 + (l15>>3), col-in-chunk = l15&7
#pragma unroll
        for (int nt = 0; nt < 4; ++nt)
#pragma unroll
            for (int r = 0; r < 4; ++r) {
                int prow   = quad*4 + r;
                int pchunk = (nt*2 + (l15 >> 3)) ^ (prow & 7);
                Pl[wave*1024 + prow*64 + pchunk*8 + (l15 & 7)] =
                    (__bf16)p[nt][r];
            }
        __syncthreads();

#pragma unroll
        for (int kc = 0; kc < 2; ++kc) {
            bf16x8 pfrag = *(const bf16x8*)((const char*)Pl + wave*2048 +
                             l15*128 + ((kc*4 + quad) ^ sw)*16);
#pragma unroll
            for (int n = 0; n < 8; ++n) {
                bf16x8 vfr = *(const bf16x8*)((const char*)Vt +
                               (n*16 + l15)*128 + ((kc*4 + quad) ^ sw)*16);
                oacc[n] = __builtin_amdgcn_mfma_f32_16x16x32_bf16(
                              pfrag, vfr, oacc[n], 0, 0, 0);
            }
        }
    }

#pragma unroll
    for (int r = 0; r < 4; ++r) {
        float inv = 1.0f / l_i[r];
        size_t base = (size_t)(qrow_base + quad*4 + r)*2048 + h*128 + l15;
#pragma unroll
        for (int n = 0; n < 8; ++n)
            o[base + n*16] = (__bf16)(oacc[n][r] * inv);
    }
}

// ---------------------------------------------------------------------------
// Orchestration
// ---------------------------------------------------------------------------
extern "C" void kernel_launch(void* const* d_in, const int* in_sizes, int n_in,
                              void* d_out, int out_size, void* d_ws, size_t ws_size,
                              hipStream_t stream) {
    (void)in_sizes; (void)n_in; (void)out_size;
    const float* hidden = (const float*)d_in[0];
    const int*   sid    = (const int*)d_in[1];
    const int*   pos    = (const int*)d_in[2];
    const float* ln1    = (const float*)d_in[3];
    const float* wq     = (const float*)d_in[4];
    const float* wk     = (const float*)d_in[5];
    const float* wv     = (const float*)d_in[6];
    const float* wo     = (const float*)d_in[7];
    const float* ln2    = (const float*)d_in[8];
    const float* wg     = (const float*)d_in[9];
    const float* wu     = (const float*)d_in[10];
    const float* wd     = (const float*)d_in[11];
    float* out = (float*)d_out;
    char*  ws  = (char*)d_ws;

    // workspace layout (lifetimes overlapped):
    __bf16* wb   = (__bf16*)(ws);                  // 0..120MB  weights bf16
    __bf16* xb   = (__bf16*)(ws + (120UL << 20));  // 120..128  x (rms1), later ob, later yb
    __bf16* qb   = (__bf16*)(ws + (128UL << 20));  // 128..136  q
    __bf16* kb   = (__bf16*)(ws + (136UL << 20));  // 136..140  k
    __bf16* vtb  = (__bf16*)(ws + (140UL << 20));  // 140..144  v^T
    __bf16* ob   = (__bf16*)(ws + (120UL << 20));  // reuse xb after qkv
    float*  hbuf = (float*) (ws + (128UL << 20));  // 128..144  reuse q/k/v after attn
    __bf16* yb   = (__bf16*)(ws + (120UL << 20));  // reuse ob after oproj
    __bf16* actb = (__bf16*)(ws + (144UL << 20));  // 144..176
    float*  pbuf = (float*) (ws + (176UL << 20));  // 176..240  split-K partials

    k_cvt<<<30720, 256, 0, stream>>>(wq, wk, wv, wo, wg, wu, wd, wb);
    k_rmsnorm<<<SEQ, 256, 0, stream>>>(hidden, ln1, xb);
    k_gemm_qkv<<<dim3(32, 16), 256, 0, stream>>>(xb, wb, pos, qb, kb, vtb);
    k_attn<<<dim3(32, 16), 256, 0, stream>>>(qb, kb, vtb, sid, ob);
    k_gemm_oproj<<<dim3(16, 16), 256, 0, stream>>>(ob, wb + OFF_WO, hidden, hbuf);
    k_rmsnorm<<<SEQ, 256, 0, stream>>>(hbuf, ln2, yb);
    // MLP: up writes u to actb, then gate reads u and writes silu(g)*u in place
    k_mlp256<<<dim3(32, 8), 512, 0, stream>>>(yb, wb + OFF_WU, actb, 0);
    k_mlp256<<<dim3(32, 8), 512, 0, stream>>>(yb, wb + OFF_WG, actb, 1);
    if (ws_size >= (240UL << 20)) {
        k_dsplit256<<<256, 512, 0, stream>>>(actb, wb + OFF_WD, pbuf);
        k_down_reduce<<<4096, 256, 0, stream>>>(pbuf, hbuf, out);
    } else {
        k_gemm_down<<<dim3(16, 16), 256, 0, stream>>>(actb, wb + OFF_WD, hbuf, out);
    }
}

// Round 5
// 678.113 us; speedup vs baseline: 1.4086x; 1.0139x over previous
//
#include <hip/hip_runtime.h>
#include <hip/hip_bf16.h>
#include <math.h>

#define SEQ    2048
#define HIDDEN 2048
#define INTER  8192
#define NHEADS 16
#define KVH    8
#define HD     128

typedef __bf16 bf16x8 __attribute__((ext_vector_type(8)));
typedef __bf16 bf16x4 __attribute__((ext_vector_type(4)));
typedef float  f32x4  __attribute__((ext_vector_type(4)));

typedef __attribute__((address_space(1))) void* as1v;
typedef __attribute__((address_space(3))) void* as3v;

__device__ __forceinline__ void g2l16(const void* g, void* l) {
    __builtin_amdgcn_global_load_lds((as1v)g, (as3v)l, 16, 0, 0);
}

// weight blob layout (elements) inside ws: wq, wk, wv, wo, wg, wu, wd
#define OFF_WQ 0UL
#define OFF_WK 4194304UL
#define OFF_WV 6291456UL
#define OFF_WO 8388608UL
#define OFF_WG 12582912UL
#define OFF_WU 29360128UL
#define OFF_WD 46137344UL
#define W_TOTAL 62914560UL

// ---------------------------------------------------------------------------
// Weight fp32 -> bf16 conversion (once per launch).  8 elems/thread.
// ---------------------------------------------------------------------------
__global__ __launch_bounds__(256) void k_cvt(
        const float* __restrict__ wq, const float* __restrict__ wk,
        const float* __restrict__ wv, const float* __restrict__ wo,
        const float* __restrict__ wg, const float* __restrict__ wu,
        const float* __restrict__ wd, __bf16* __restrict__ wb) {
    size_t e = ((size_t)blockIdx.x * 256 + threadIdx.x) * 8;
    const float* src; size_t base;
    if      (e < OFF_WK) { src = wq; base = OFF_WQ; }
    else if (e < OFF_WV) { src = wk; base = OFF_WK; }
    else if (e < OFF_WO) { src = wv; base = OFF_WV; }
    else if (e < OFF_WG) { src = wo; base = OFF_WO; }
    else if (e < OFF_WU) { src = wg; base = OFF_WG; }
    else if (e < OFF_WD) { src = wu; base = OFF_WU; }
    else                 { src = wd; base = OFF_WD; }
    const float4* s = (const float4*)(src + (e - base));
    float4 a = s[0], b = s[1];
    bf16x8 o;
    o[0] = (__bf16)a.x; o[1] = (__bf16)a.y; o[2] = (__bf16)a.z; o[3] = (__bf16)a.w;
    o[4] = (__bf16)b.x; o[5] = (__bf16)b.y; o[6] = (__bf16)b.z; o[7] = (__bf16)b.w;
    *(bf16x8*)(wb + e) = o;
}

// ---------------------------------------------------------------------------
// RMSNorm (fp32 in) -> bf16 out.  One block per row of 2048.
// ---------------------------------------------------------------------------
__global__ __launch_bounds__(256) void k_rmsnorm(const float* __restrict__ x,
                                                 const float* __restrict__ w,
                                                 __bf16* __restrict__ out) {
    int row = blockIdx.x;
    int t   = threadIdx.x;
    const float4* xr = (const float4*)(x + (size_t)row * HIDDEN);
    float4 a = xr[t];
    float4 b = xr[t + 256];
    float ss = a.x*a.x + a.y*a.y + a.z*a.z + a.w*a.w
             + b.x*b.x + b.y*b.y + b.z*b.z + b.w*b.w;
#pragma unroll
    for (int d = 32; d > 0; d >>= 1) ss += __shfl_xor(ss, d);
    __shared__ float red[4];
    if ((t & 63) == 0) red[t >> 6] = ss;
    __syncthreads();
    float tot = red[0] + red[1] + red[2] + red[3];
    float r = rsqrtf(tot * (1.0f / (float)HIDDEN) + 1e-6f);
    const float4* wr = (const float4*)w;
    float4 wa = wr[t], wb = wr[t + 256];
    __bf16* o = out + (size_t)row * HIDDEN;
    bf16x4 pa, pb;
    pa[0] = (__bf16)(a.x * r * wa.x);
    pa[1] = (__bf16)(a.y * r * wa.y);
    pa[2] = (__bf16)(a.z * r * wa.z);
    pa[3] = (__bf16)(a.w * r * wa.w);
    pb[0] = (__bf16)(b.x * r * wb.x);
    pb[1] = (__bf16)(b.y * r * wb.y);
    pb[2] = (__bf16)(b.z * r * wb.z);
    pb[3] = (__bf16)(b.w * r * wb.w);
    *(bf16x4*)(o + 4*t)        = pa;
    *(bf16x4*)(o + 4*t + 1024) = pb;
}

// ---------------------------------------------------------------------------
// Pure-bf16 GEMM core, m97 structure (proven): C[128x128] tile.
// ---------------------------------------------------------------------------
__device__ __forceinline__ int gncol(int wn, int nt, int l15) {
    return wn*32 + ((nt & 1) << 4) + ((nt >> 1) << 6) + l15;
}

__device__ __forceinline__ void gemm_core(const __bf16* __restrict__ A, int lda,
                                          const __bf16* __restrict__ B, int ldb,
                                          int K, int m0, int n0,
                                          __bf16* As, __bf16* Bs,
                                          f32x4 acc[4][4]) {
    int tid  = threadIdx.x;
    int wave = tid >> 6;
    int lane = tid & 63;
    int quad = lane >> 4;
    int l15  = lane & 15;
    int wm = wave >> 1, wn = wave & 1;

    int srow = wave*32 + (lane >> 2);
    int scol = (lane & 3) * 8;
    char* adst = (char*)As + wave*2048 + lane*16;
    char* bdst = (char*)Bs + wave*2048 + lane*16;

    for (int k0 = 0; k0 < K; k0 += 32) {
        __syncthreads();
        g2l16(A + (size_t)(m0 + srow)      * lda + k0 + scol, adst);
        g2l16(A + (size_t)(m0 + srow + 16) * lda + k0 + scol, adst + 1024);
        g2l16(B + (size_t)(n0 + srow)      * ldb + k0 + scol, bdst);
        g2l16(B + (size_t)(n0 + srow + 16) * ldb + k0 + scol, bdst + 1024);
        __syncthreads();

        bf16x8 af[4], bfr[4];
#pragma unroll
        for (int mt = 0; mt < 4; ++mt)
            af[mt] = *(const bf16x8*)((const char*)As +
                        (wm*64 + mt*16 + l15)*64 + quad*16);
#pragma unroll
        for (int nt = 0; nt < 4; ++nt) {
            int r = gncol(wn, nt, l15);
            bfr[nt] = *(const bf16x8*)((const char*)Bs + r*64 + quad*16);
        }
#pragma unroll
        for (int mt = 0; mt < 4; ++mt)
#pragma unroll
            for (int nt = 0; nt < 4; ++nt)
                acc[mt][nt] = __builtin_amdgcn_mfma_f32_16x16x32_bf16(
                                  af[mt], bfr[nt], acc[mt][nt], 0, 0, 0);
    }
}

__device__ __forceinline__ void zero_acc(f32x4 acc[4][4]) {
#pragma unroll
    for (int i = 0; i < 4; ++i)
#pragma unroll
        for (int j = 0; j < 4; ++j) {
            acc[i][j][0] = 0.f; acc[i][j][1] = 0.f;
            acc[i][j][2] = 0.f; acc[i][j][3] = 0.f;
        }
}

// ---------------------------------------------------------------------------
// 256x256-tile 8-phase pipelined GEMM core (m201-style, plain HIP).
// 8 waves (2M x 4N), per-wave C = 128x64; BK=64, double-buffered 128 KiB LDS.
// Bank swizzle chunk^=row&7 via pre-swizzled global source + swizzled read.
// Counted vmcnt(4) at phases 4/8 only.  Generalized over row strides ldA/ldB
// (kernels define Ag/Bg/ldA/ldB before using the macros).
// ---------------------------------------------------------------------------
#define MFMA_BF16 __builtin_amdgcn_mfma_f32_16x16x32_bf16
#define VMC asm volatile("s_waitcnt vmcnt(4)" ::: "memory")
#define NOSTMT ((void)0)

#define STAGE_A(BUF, HALF, TILE) do {                                         \
    const __bf16* _s = Ag + (size_t)(m0 + (HALF)*128 + stgRow) * ldA          \
                      + ((size_t)(TILE) << 6) + stgCol;                       \
    char* _d = (char*)smem + (BUF)*65536 + (HALF)*16384 + stgDst;             \
    g2l16(_s, _d);                                                            \
    g2l16(_s + 8*ldA, _d + 1024);                                             \
} while (0)

#define STAGE_B(BUF, HALF, TILE) do {                                         \
    const __bf16* _s = Bg + (size_t)(n0 + (HALF)*128 + stgRow) * ldB          \
                      + ((size_t)(TILE) << 6) + stgCol;                       \
    char* _d = (char*)smem + (BUF)*65536 + 32768 + (HALF)*16384 + stgDst;     \
    g2l16(_s, _d);                                                            \
    g2l16(_s + 8*ldB, _d + 1024);                                             \
} while (0)

#define PHASE(BUF, MH, NH, STAGE_STMT, VMWAIT) do {                           \
    bf16x8 _af[4][2], _bf[2][2];                                              \
    {                                                                         \
        const char* _Ab = (const char*)smem + (BUF)*65536 + (MH)*16384 + aRow;\
        const char* _Bb = (const char*)smem + (BUF)*65536 + 32768             \
                          + (NH)*16384 + bRow;                                \
        _Pragma("unroll")                                                     \
        for (int _m = 0; _m < 4; ++_m) {                                      \
            _af[_m][0] = *(const bf16x8*)(_Ab + _m*2048 + off0);              \
            _af[_m][1] = *(const bf16x8*)(_Ab + _m*2048 + (off0^64));         \
        }                                                                     \
        _Pragma("unroll")                                                     \
        for (int _n = 0; _n < 2; ++_n) {                                      \
            _bf[_n][0] = *(const bf16x8*)(_Bb + _n*2048 + off0);              \
            _bf[_n][1] = *(const bf16x8*)(_Bb + _n*2048 + (off0^64));         \
        }                                                                     \
    }                                                                         \
    STAGE_STMT;                                                               \
    VMWAIT;                                                                   \
    asm volatile("" ::: "memory");                                            \
    __builtin_amdgcn_s_barrier();                                             \
    asm volatile("" ::: "memory");                                            \
    __builtin_amdgcn_s_setprio(1);                                            \
    _Pragma("unroll")                                                         \
    for (int _m = 0; _m < 4; ++_m)                                            \
        _Pragma("unroll")                                                     \
        for (int _n = 0; _n < 2; ++_n) {                                      \
            acc[MH][NH][_m][_n] = MFMA_BF16(_af[_m][0], _bf[_n][0],           \
                                            acc[MH][NH][_m][_n], 0, 0, 0);    \
            acc[MH][NH][_m][_n] = MFMA_BF16(_af[_m][1], _bf[_n][1],           \
                                            acc[MH][NH][_m][_n], 0, 0, 0);    \
        }                                                                     \
    __builtin_amdgcn_s_setprio(0);                                            \
    asm volatile("" ::: "memory");                                            \
    __builtin_amdgcn_s_barrier();                                             \
    asm volatile("" ::: "memory");                                            \
} while (0)

#define P256_PRE                                                              \
    int tid  = threadIdx.x;                                                   \
    int wave = tid >> 6, lane = tid & 63;                                     \
    int wm = wave >> 2, wn = wave & 3;                                        \
    int quad = lane >> 4, l15 = lane & 15;                                    \
    int cx   = l15 & 7;                                                       \
    int off0 = (quad ^ cx) << 4;                                              \
    int aRow = (wm*64 + l15) << 7;                                            \
    int bRow = (wn*32 + l15) << 7;                                            \
    int stgRow = wave*16 + (lane >> 3);                                       \
    int stgCol = ((lane & 7) ^ (lane >> 3)) << 3;                             \
    int stgDst = wave*2048 + lane*16;                                         \
    f32x4 acc[2][2][4][2];                                                    \
    _Pragma("unroll")                                                         \
    for (int _a = 0; _a < 2; ++_a)                                            \
        _Pragma("unroll")                                                     \
        for (int _b = 0; _b < 2; ++_b)                                        \
            _Pragma("unroll")                                                 \
            for (int _c = 0; _c < 4; ++_c)                                    \
                _Pragma("unroll")                                             \
                for (int _d = 0; _d < 2; ++_d) {                              \
                    acc[_a][_b][_c][_d][0] = 0.f; acc[_a][_b][_c][_d][1] = 0.f;\
                    acc[_a][_b][_c][_d][2] = 0.f; acc[_a][_b][_c][_d][3] = 0.f;\
                }

#define P256_LOOP(NT)                                                         \
    STAGE_A(0, 0, 0); STAGE_B(0, 0, 0);                                       \
    STAGE_A(0, 1, 0); STAGE_B(0, 1, 0);                                       \
    STAGE_A(1, 0, 1); STAGE_B(1, 0, 1);                                       \
    VMC;                                                                      \
    asm volatile("" ::: "memory");                                            \
    __builtin_amdgcn_s_barrier();                                             \
    asm volatile("" ::: "memory");                                            \
    for (int i = 0; i < (NT)/2; ++i) {                                        \
        int t1 = (2*i + 1) & ((NT)-1);                                        \
        int t2 = (2*i + 2) & ((NT)-1);                                        \
        int t3 = (2*i + 3) & ((NT)-1);                                        \
        PHASE(0, 0, 0, STAGE_A(1, 1, t1), NOSTMT);                            \
        PHASE(0, 0, 1, STAGE_B(1, 1, t1), NOSTMT);                            \
        PHASE(0, 1, 0, STAGE_A(0, 0, t2), NOSTMT);                            \
        PHASE(0, 1, 1, STAGE_B(0, 0, t2), VMC);                               \
        PHASE(1, 0, 0, STAGE_A(0, 1, t2), NOSTMT);                            \
        PHASE(1, 0, 1, STAGE_B(0, 1, t2), NOSTMT);                            \
        PHASE(1, 1, 0, STAGE_A(1, 0, t3), NOSTMT);                            \
        PHASE(1, 1, 1, STAGE_B(1, 0, t3), VMC);                               \
    }

// mode 0: outb = A@W^T (bf16).  mode 1: outb = silu(A@W^T) * outb (in place).
__global__ __launch_bounds__(512, 2) void k_mlp256(
        const __bf16* __restrict__ Aptr,   // [2048][2048] bf16
        const __bf16* __restrict__ Bptr,   // [8192][2048] bf16
        __bf16* __restrict__ outb,         // [2048][8192] bf16
        int mode) {
    __shared__ char smem[131072];

    // XCD-aware swizzle: 256 wgs, 8 XCDs, each XCD owns one 256-row m-stripe
    int flat = blockIdx.y * 32 + blockIdx.x;          // grid = (32, 8)
    int swz  = (flat & 7) * 32 + (flat >> 3);
    int m0 = (swz >> 5) * 256;
    int n0 = (swz & 31) * 256;
    const __bf16* Ag = Aptr;
    const __bf16* Bg = Bptr;
    const int ldA = 2048, ldB = 2048;

    P256_PRE;
    P256_LOOP(32);

    // epilogue
    int gm0 = m0 + wm*64 + quad*4;
    int gn0 = n0 + wn*32 + l15;
    if (mode == 0) {
#pragma unroll
        for (int mh = 0; mh < 2; ++mh)
#pragma unroll
            for (int nh = 0; nh < 2; ++nh)
#pragma unroll
                for (int mt2 = 0; mt2 < 4; ++mt2)
#pragma unroll
                    for (int nt2 = 0; nt2 < 2; ++nt2)
#pragma unroll
                        for (int r = 0; r < 4; ++r) {
                            int gm = gm0 + mh*128 + mt2*16 + r;
                            int gn = gn0 + nh*128 + nt2*16;
                            outb[(size_t)gm*INTER + gn] =
                                (__bf16)acc[mh][nh][mt2][nt2][r];
                        }
    } else {
#pragma unroll
        for (int mh = 0; mh < 2; ++mh)
#pragma unroll
            for (int nh = 0; nh < 2; ++nh)
#pragma unroll
                for (int mt2 = 0; mt2 < 4; ++mt2)
#pragma unroll
                    for (int nt2 = 0; nt2 < 2; ++nt2)
#pragma unroll
                        for (int r = 0; r < 4; ++r) {
                            int gm = gm0 + mh*128 + mt2*16 + r;
                            int gn = gn0 + nh*128 + nt2*16;
                            size_t idx = (size_t)gm*INTER + gn;
                            float g = acc[mh][nh][mt2][nt2][r];
                            float u = (float)outb[idx];
                            float s = g / (1.0f + __expf(-g));
                            outb[idx] = (__bf16)(s * u);
                        }
    }
}

// ---------------------------------------------------------------------------
// Split-K down GEMM: partial[kz] = act[:, kz*2048:+2048] @ wd[:, same]^T.
// 256 blocks = 8m x 8n x 4kz, fp32 partials [4][2048][2048].
// ---------------------------------------------------------------------------
__global__ __launch_bounds__(512, 2) void k_dsplit256(
        const __bf16* __restrict__ Aptr,   // act [2048][8192] bf16
        const __bf16* __restrict__ Bptr,   // wd  [2048][8192] bf16
        float* __restrict__ pbuf) {        // [4][2048][2048] fp32
    __shared__ char smem[131072];

    int flat = blockIdx.x;                            // 0..255
    int swz  = (flat & 7) * 32 + (flat >> 3);         // XCD chunking
    int kz = swz >> 6;                                // 0..3
    int m0 = ((swz >> 3) & 7) * 256;
    int n0 = (swz & 7) * 256;
    const __bf16* Ag = Aptr + (size_t)kz * 2048;      // column offset into K
    const __bf16* Bg = Bptr + (size_t)kz * 2048;
    const int ldA = 8192, ldB = 8192;

    P256_PRE;
    P256_LOOP(32);

    float* pout = pbuf + (size_t)kz * 4194304;
    int gm0 = m0 + wm*64 + quad*4;
    int gn0 = n0 + wn*32 + l15;
#pragma unroll
    for (int mh = 0; mh < 2; ++mh)
#pragma unroll
        for (int nh = 0; nh < 2; ++nh)
#pragma unroll
            for (int mt2 = 0; mt2 < 4; ++mt2)
#pragma unroll
                for (int nt2 = 0; nt2 < 2; ++nt2)
#pragma unroll
                    for (int r = 0; r < 4; ++r) {
                        int gm = gm0 + mh*128 + mt2*16 + r;
                        int gn = gn0 + nh*128 + nt2*16;
                        pout[(size_t)gm*HIDDEN + gn] = acc[mh][nh][mt2][nt2][r];
                    }
}

// out = h + p0 + p1 + p2 + p3   (all fp32, 2048x2048)
__global__ __launch_bounds__(256) void k_down_reduce(
        const float* __restrict__ p, const float* __restrict__ h,
        float* __restrict__ out) {
    size_t i = ((size_t)blockIdx.x * 256 + threadIdx.x) * 4;
    float4 a = *(const float4*)(p + i);
    float4 b = *(const float4*)(p + 4194304 + i);
    float4 c = *(const float4*)(p + 8388608 + i);
    float4 d = *(const float4*)(p + 12582912 + i);
    float4 hh = *(const float4*)(h + i);
    float4 o;
    o.x = a.x + b.x + c.x + d.x + hh.x;
    o.y = a.y + b.y + c.y + d.y + hh.y;
    o.z = a.z + b.z + c.z + d.z + hh.z;
    o.w = a.w + b.w + c.w + d.w + hh.w;
    *(float4*)(out + i) = o;
}

// ---------------------------------------------------------------------------
// Fused QKV GEMM + RoPE + V-transpose.
// ---------------------------------------------------------------------------
__global__ __launch_bounds__(256) void k_gemm_qkv(
        const __bf16* __restrict__ x, const __bf16* __restrict__ wb,
        const int* __restrict__ pos_ids,
        __bf16* __restrict__ qb, __bf16* __restrict__ kb,
        __bf16* __restrict__ vtb) {
    __shared__ __bf16 As[128*32];
    __shared__ __bf16 Bs[128*32];
    int bn = blockIdx.x;
    int m0 = blockIdx.y * 128;
    const __bf16* B; int n0; int kind;
    if (bn < 16)      { B = wb + OFF_WQ; n0 = bn*128;      kind = 0; }
    else if (bn < 24) { B = wb + OFF_WK; n0 = (bn-16)*128; kind = 1; }
    else              { B = wb + OFF_WV; n0 = (bn-24)*128; kind = 2; }
    f32x4 acc[4][4]; zero_acc(acc);
    gemm_core(x, HIDDEN, B, HIDDEN, HIDDEN, m0, n0, As, Bs, acc);

    int tid = threadIdx.x, wave = tid >> 6, lane = tid & 63;
    int quad = lane >> 4, l15 = lane & 15, wm = wave >> 1, wn = wave & 1;

    if (kind == 2) {
#pragma unroll
        for (int mt = 0; mt < 4; ++mt)
#pragma unroll
            for (int nt = 0; nt < 4; ++nt) {
                int f  = n0 + gncol(wn, nt, l15);
                int gm = m0 + wm*64 + mt*16 + quad*4;
                bf16x4 vv;
                vv[0] = (__bf16)acc[mt][nt][0];
                vv[1] = (__bf16)acc[mt][nt][1];
                vv[2] = (__bf16)acc[mt][nt][2];
                vv[3] = (__bf16)acc[mt][nt][3];
                *(bf16x4*)(vtb + (size_t)f*2048 + gm) = vv;
            }
    } else {
        __bf16* out = (kind == 0) ? qb : kb;
        int ldc     = (kind == 0) ? 2048 : 1024;
        float scale = (kind == 0) ? 0.08838834764831845f : 1.0f;
        int i0 = wn*32 + l15;
        const float LN1E4_64 = 0.14391156831212787f;
        float f0 = __expf(-LN1E4_64 * (float)i0);
        float f1 = __expf(-LN1E4_64 * (float)(i0 + 16));
#pragma unroll
        for (int mt = 0; mt < 4; ++mt)
#pragma unroll
            for (int r = 0; r < 4; ++r) {
                int gm = m0 + wm*64 + mt*16 + quad*4 + r;
                float pos = (float)pos_ids[gm];
                float s0, c0, s1, c1;
                __sincosf(pos * f0, &s0, &c0);
                __sincosf(pos * f1, &s1, &c1);
                float a0 = acc[mt][0][r], a1 = acc[mt][1][r];
                float a2 = acc[mt][2][r], a3 = acc[mt][3][r];
                size_t rowb = (size_t)gm * ldc + n0 + wn*32 + l15;
                out[rowb]      = (__bf16)((a0*c0 - a2*s0) * scale);
                out[rowb + 16] = (__bf16)((a1*c1 - a3*s1) * scale);
                out[rowb + 64] = (__bf16)((a2*c0 + a0*s0) * scale);
                out[rowb + 80] = (__bf16)((a3*c1 + a1*s1) * scale);
            }
    }
}

// ---------------------------------------------------------------------------
// O-projection + residual: h = resid + o @ wo^T  (fp32 out)
// ---------------------------------------------------------------------------
__global__ __launch_bounds__(256) void k_gemm_oproj(
        const __bf16* __restrict__ ob, const __bf16* __restrict__ wo,
        const float* __restrict__ resid, float* __restrict__ h) {
    __shared__ __bf16 As[128*32];
    __shared__ __bf16 Bs[128*32];
    int n0 = blockIdx.x * 128, m0 = blockIdx.y * 128;
    f32x4 acc[4][4]; zero_acc(acc);
    gemm_core(ob, HIDDEN, wo, HIDDEN, HIDDEN, m0, n0, As, Bs, acc);
    int lane = threadIdx.x & 63, wave = threadIdx.x >> 6;
    int quad = lane >> 4, l15 = lane & 15, wm = wave >> 1, wn = wave & 1;
#pragma unroll
    for (int mt = 0; mt < 4; ++mt)
#pragma unroll
        for (int nt = 0; nt < 4; ++nt)
#pragma unroll
            for (int r = 0; r < 4; ++r) {
                int gm = m0 + wm*64 + mt*16 + quad*4 + r;
                int gn = n0 + gncol(wn, nt, l15);
                size_t idx = (size_t)gm*HIDDEN + gn;
                h[idx] = acc[mt][nt][r] + resid[idx];
            }
}

// ---------------------------------------------------------------------------
// Down GEMM + residual (fallback when workspace too small for split-K)
// ---------------------------------------------------------------------------
__global__ __launch_bounds__(256) void k_gemm_down(
        const __bf16* __restrict__ act, const __bf16* __restrict__ wd,
        const float* __restrict__ h, float* __restrict__ out) {
    __shared__ __bf16 As[128*32];
    __shared__ __bf16 Bs[128*32];
    int n0 = blockIdx.x * 128, m0 = blockIdx.y * 128;
    f32x4 acc[4][4]; zero_acc(acc);
    gemm_core(act, INTER, wd, INTER, INTER, m0, n0, As, Bs, acc);
    int lane = threadIdx.x & 63, wave = threadIdx.x >> 6;
    int quad = lane >> 4, l15 = lane & 15, wm = wave >> 1, wn = wave & 1;
#pragma unroll
    for (int mt = 0; mt < 4; ++mt)
#pragma unroll
        for (int nt = 0; nt < 4; ++nt)
#pragma unroll
            for (int r = 0; r < 4; ++r) {
                int gm = m0 + wm*64 + mt*16 + quad*4 + r;
                int gn = n0 + gncol(wn, nt, l15);
                size_t idx = (size_t)gm*HIDDEN + gn;
                out[idx] = acc[mt][nt][r] + h[idx];
            }
}

// ---------------------------------------------------------------------------
// Flash attention with same-sid + causal mask.
// LDS tiles XOR-swizzled (chunk ^= row&7); see round-4 notes.
// Triangular load balance: work per block is qt+1 k-tiles.  Linear dispatch
// pairs block c (head h<8) with block c+256 (head h>=8) on the same CU slot;
// with the naive map both have the SAME qt -> CUs get 2..64 tiles (2x skew,
// half the machine idles; measured Occupancy 10.9%).  Reversing qt for the
// upper heads makes every pair sum to exactly 33 tiles.
// ---------------------------------------------------------------------------
__global__ __launch_bounds__(256) void k_attn(
        const __bf16* __restrict__ qb,   // [2048,2048] rope'd, pre-scaled
        const __bf16* __restrict__ kb,   // [2048,1024] rope'd
        const __bf16* __restrict__ vt,   // [1024][2048] transposed
        const int* __restrict__ sid,     // [2048]
        __bf16* __restrict__ o) {        // [2048,2048]
    __shared__ int    sid_lds[SEQ];        // 8KB
    __shared__ __bf16 Kt[64*128];          // 16KB [key][d], swizzled
    __shared__ __bf16 Vt[128*64];          // 16KB [d][key], swizzled
    __shared__ __bf16 Pl[4*1024];          // 8KB, per-wave 16x64, swizzled

    int h  = blockIdx.y;          // 0..15
    int qt = (h & 8) ? (31 - blockIdx.x) : blockIdx.x;   // balanced pairing
    int hk = h >> 1;              // GQA: rep=2
    int tid = threadIdx.x, wave = tid >> 6, lane = tid & 63;
    int quad = lane >> 4, l15 = lane & 15;
    int q0 = qt * 64;
    int qrow_base = q0 + wave * 16;
    int sw = l15 & 7;             // read-side swizzle key (row&7 == l15&7)

    for (int i = tid; i < SEQ; i += 256) sid_lds[i] = sid[i];

    bf16x8 qfrag[4];
#pragma unroll
    for (int seg = 0; seg < 4; ++seg)
        qfrag[seg] = *(const bf16x8*)(qb + (size_t)(qrow_base + l15)*2048
                                         + h*128 + seg*32 + quad*8);
    __syncthreads();
    int sq[4];
#pragma unroll
    for (int r = 0; r < 4; ++r) sq[r] = sid_lds[qrow_base + quad*4 + r];

    float m_i[4], l_i[4];
    f32x4 oacc[8];
#pragma unroll
    for (int r = 0; r < 4; ++r) { m_i[r] = -INFINITY; l_i[r] = 0.f; }
#pragma unroll
    for (int n = 0; n < 8; ++n) {
        oacc[n][0] = 0.f; oacc[n][1] = 0.f; oacc[n][2] = 0.f; oacc[n][3] = 0.f;
    }

    // staging source-chunk swizzles (match the read-side XOR):
    // K: row = c*4 + (lane>>4), 16 chunks/row; srcChunkK = (lane&15) ^ (row&7)
    // V: row = c*8 + (lane>>3),  8 chunks/row; srcChunkV = (lane&7)  ^ (row&7)
    int kRowPar = lane >> 4;                 // row&3 contribution (K)
    int vRowPar = lane >> 3;                 // row&7 (V)

    for (int kt = 0; kt <= qt; ++kt) {
        int k0 = kt * 64;
        __syncthreads();
#pragma unroll
        for (int t2 = 0; t2 < 4; ++t2) {
            int c    = wave*4 + t2;
            int row  = c*4 + kRowPar;
            int rk   = ((c & 1) << 2) + kRowPar;       // row&7
            int srcC = (lane & 15) ^ rk;
            g2l16(kb + (size_t)(k0 + row)*1024 + hk*128 + srcC*8,
                  (char*)Kt + c*1024 + lane*16);
        }
#pragma unroll
        for (int t2 = 0; t2 < 4; ++t2) {
            int c    = wave*4 + t2;
            int row  = c*8 + vRowPar;
            int srcC = (lane & 7) ^ vRowPar;           // row&7 == lane>>3
            g2l16(vt + (size_t)(hk*128 + row)*2048 + k0 + srcC*8,
                  (char*)Vt + c*1024 + lane*16);
        }
        __syncthreads();

        f32x4 sacc[4];
#pragma unroll
        for (int nt = 0; nt < 4; ++nt) {
            sacc[nt][0]=0.f; sacc[nt][1]=0.f; sacc[nt][2]=0.f; sacc[nt][3]=0.f;
        }
#pragma unroll
        for (int seg = 0; seg < 4; ++seg)
#pragma unroll
            for (int nt = 0; nt < 4; ++nt) {
                bf16x8 kfr = *(const bf16x8*)((const char*)Kt +
                               (nt*16 + l15)*256 + ((seg*4 + quad) ^ sw)*16);
                sacc[nt] = __builtin_amdgcn_mfma_f32_16x16x32_bf16(
                               qfrag[seg], kfr, sacc[nt], 0, 0, 0);
            }

        int sk[4], kg[4];
#pragma unroll
        for (int nt = 0; nt < 4; ++nt) {
            kg[nt] = k0 + nt*16 + l15;
            sk[nt] = sid_lds[kg[nt]];
        }
        float p[4][4];
#pragma unroll
        for (int r = 0; r < 4; ++r) {
            int qg = qrow_base + quad*4 + r;
            float mx = -INFINITY;
#pragma unroll
            for (int nt = 0; nt < 4; ++nt) {
                bool valid = (kg[nt] <= qg) && (sk[nt] == sq[r]);
                float s = valid ? sacc[nt][r] : -INFINITY;
                p[nt][r] = s;
                mx = fmaxf(mx, s);
            }
            mx = fmaxf(mx, __shfl_xor(mx, 1));
            mx = fmaxf(mx, __shfl_xor(mx, 2));
            mx = fmaxf(mx, __shfl_xor(mx, 4));
            mx = fmaxf(mx, __shfl_xor(mx, 8));
            float mn = fmaxf(m_i[r], mx);
            float alpha = (mn == m_i[r]) ? 1.0f : __expf(m_i[r] - mn);
            float rs = 0.f;
#pragma unroll
            for (int nt = 0; nt < 4; ++nt) {
                float pv = (p[nt][r] == -INFINITY) ? 0.f : __expf(p[nt][r] - mn);
                p[nt][r] = pv;
                rs += pv;
            }
            rs += __shfl_xor(rs, 1);
            rs += __shfl_xor(rs, 2);
            rs += __shfl_xor(rs, 4);
            rs += __shfl_xor(rs, 8);
            l_i[r] = l_i[r] * alpha + rs;
            m_i[r] = mn;
#pragma unroll
            for (int n = 0; n < 8; ++n) oacc[n][r] *= alpha;
        }

        // P write, swizzled: row = quad*4+r (16 rows x 64 cols, 128B rows,
        // 8 chunks/row); chunk = nt*2 + (l15>>3), col-in-chunk = l15&7
#pragma unroll
        for (int nt = 0; nt < 4; ++nt)
#pragma unroll
            for (int r = 0; r < 4; ++r) {
                int prow   = quad*4 + r;
                int pchunk = (nt*2 + (l15 >> 3)) ^ (prow & 7);
                Pl[wave*1024 + prow*64 + pchunk*8 + (l15 & 7)] =
                    (__bf16)p[nt][r];
            }
        __syncthreads();

#pragma unroll
        for (int kc = 0; kc < 2; ++kc) {
            bf16x8 pfrag = *(const bf16x8*)((const char*)Pl + wave*2048 +
                             l15*128 + ((kc*4 + quad) ^ sw)*16);
#pragma unroll
            for (int n = 0; n < 8; ++n) {
                bf16x8 vfr = *(const bf16x8*)((const char*)Vt +
                               (n*16 + l15)*128 + ((kc*4 + quad) ^ sw)*16);
                oacc[n] = __builtin_amdgcn_mfma_f32_16x16x32_bf16(
                              pfrag, vfr, oacc[n], 0, 0, 0);
            }
        }
    }

#pragma unroll
    for (int r = 0; r < 4; ++r) {
        float inv = 1.0f / l_i[r];
        size_t base = (size_t)(qrow_base + quad*4 + r)*2048 + h*128 + l15;
#pragma unroll
        for (int n = 0; n < 8; ++n)
            o[base + n*16] = (__bf16)(oacc[n][r] * inv);
    }
}

// ---------------------------------------------------------------------------
// Orchestration
// ---------------------------------------------------------------------------
extern "C" void kernel_launch(void* const* d_in, const int* in_sizes, int n_in,
                              void* d_out, int out_size, void* d_ws, size_t ws_size,
                              hipStream_t stream) {
    (void)in_sizes; (void)n_in; (void)out_size;
    const float* hidden = (const float*)d_in[0];
    const int*   sid    = (const int*)d_in[1];
    const int*   pos    = (const int*)d_in[2];
    const float* ln1    = (const float*)d_in[3];
    const float* wq     = (const float*)d_in[4];
    const float* wk     = (const float*)d_in[5];
    const float* wv     = (const float*)d_in[6];
    const float* wo     = (const float*)d_in[7];
    const float* ln2    = (const float*)d_in[8];
    const float* wg     = (const float*)d_in[9];
    const float* wu     = (const float*)d_in[10];
    const float* wd     = (const float*)d_in[11];
    float* out = (float*)d_out;
    char*  ws  = (char*)d_ws;

    // workspace layout (lifetimes overlapped):
    __bf16* wb   = (__bf16*)(ws);                  // 0..120MB  weights bf16
    __bf16* xb   = (__bf16*)(ws + (120UL << 20));  // 120..128  x (rms1), later ob, later yb
    __bf16* qb   = (__bf16*)(ws + (128UL << 20));  // 128..136  q
    __bf16* kb   = (__bf16*)(ws + (136UL << 20));  // 136..140  k
    __bf16* vtb  = (__bf16*)(ws + (140UL << 20));  // 140..144  v^T
    __bf16* ob   = (__bf16*)(ws + (120UL << 20));  // reuse xb after qkv
    float*  hbuf = (float*) (ws + (128UL << 20));  // 128..144  reuse q/k/v after attn
    __bf16* yb   = (__bf16*)(ws + (120UL << 20));  // reuse ob after oproj
    __bf16* actb = (__bf16*)(ws + (144UL << 20));  // 144..176
    float*  pbuf = (float*) (ws + (176UL << 20));  // 176..240  split-K partials

    k_cvt<<<30720, 256, 0, stream>>>(wq, wk, wv, wo, wg, wu, wd, wb);
    k_rmsnorm<<<SEQ, 256, 0, stream>>>(hidden, ln1, xb);
    k_gemm_qkv<<<dim3(32, 16), 256, 0, stream>>>(xb, wb, pos, qb, kb, vtb);
    k_attn<<<dim3(32, 16), 256, 0, stream>>>(qb, kb, vtb, sid, ob);
    k_gemm_oproj<<<dim3(16, 16), 256, 0, stream>>>(ob, wb + OFF_WO, hidden, hbuf);
    k_rmsnorm<<<SEQ, 256, 0, stream>>>(hbuf, ln2, yb);
    // MLP: up writes u to actb, then gate reads u and writes silu(g)*u in place
    k_mlp256<<<dim3(32, 8), 512, 0, stream>>>(yb, wb + OFF_WU, actb, 0);
    k_mlp256<<<dim3(32, 8), 512, 0, stream>>>(yb, wb + OFF_WG, actb, 1);
    if (ws_size >= (240UL << 20)) {
        k_dsplit256<<<256, 512, 0, stream>>>(actb, wb + OFF_WD, pbuf);
        k_down_reduce<<<4096, 256, 0, stream>>>(pbuf, hbuf, out);
    } else {
        k_gemm_down<<<dim3(16, 16), 256, 0, stream>>>(actb, wb + OFF_WD, hbuf, out);
    }
}